// Round 6
// baseline (334.853 us; speedup 1.0000x reference)
//
#include <hip/hip_runtime.h>
#include <hip/hip_bf16.h>
#include <math.h>

// A1SparseCoding: STFT(512,160,hann,center=False) -> |.| -> per-sample norm ->
// LCA (50 iters, lam=0.5, tau=10) -> softshrink(u)
// B=8192, SEG=3200, T=17 frames, F=257 freqs, K=17*257=4369 (pad 4384), N=128 bases.
// spec stored [b][t*257+f]; D's columns permuted identically (dot products invariant).
// STFT: two real frames packed as one complex FFT (a+ib), radix-8 DIT, fp32,
// rotor-recurrence twiddles (R0 form; table variants R2/R3 latency-bound, reverted).
// R4: per-frame moments fused into k_stft epilogue; k_gemm M=32/wave K-split 8.
// R5 diagnostic finding: harness re-poison = 2x 400MiB fillBuffer ~120us INSIDE the
// timed iteration (fixed overhead); launch boundary ~5-7us each.
// R6: k_stft un-split; dprep+gram_mm+gram_fin collapsed into ONE k_prep kernel
// (gram = D*D^T is column-permutation invariant -> gram strips read raw D with
// inline f2bf, full-K per strip, symmetric k-order, no pgram/fin). 6->4 launches.

typedef short bf16x8 __attribute__((ext_vector_type(8)));
typedef float f32x4  __attribute__((ext_vector_type(4)));

#define TWO_PI_OVER_512 0.01227184630f
#define TWO_PI_OVER_64  0.09817477042f
#define C8 0.70710678118654752f

__device__ __forceinline__ unsigned short f2bf(float f){
  unsigned int u = __float_as_uint(f);
  u += 0x7FFFu + ((u >> 16) & 1u);      // RNE; inputs finite
  return (unsigned short)(u >> 16);
}
__device__ __forceinline__ float sshrink(float u){
  float a = fabsf(u) - 0.5f;
  return a > 0.0f ? copysignf(a, u) : 0.0f;
}

// ---------------- P1: fused D-prep + gram -----------------------------------
// blocks 0..127: Dbf[n][k'] bf16 permute + rowsum (row n = blockIdx).
// blocks 128..135: gram strip x = blk-128 (16 rows x 128 cols) from RAW D
//   (permutation-invariant), full K per strip -> exact symmetry; writes
//   gram_bf directly (minus eye). 4 waves, wave w owns col-tiles {2w, 2w+1}.
__global__ __launch_bounds__(256) void k_prep(const float* __restrict__ D,
    unsigned short* __restrict__ Dbf, float* __restrict__ rowsum,
    unsigned short* __restrict__ gram_bf){
  __shared__ float row[4369];
  __shared__ float rs[256];
  const int blk = blockIdx.x, tid = threadIdx.x;
  if (blk < 128){
    const int n = blk;
    float acc = 0.0f;
    for (int k = tid; k < 4369; k += 256){
      float v = D[(size_t)n*4369 + k];        // coalesced
      row[k] = v;
      acc += v;
    }
    rs[tid] = acc;
    __syncthreads();
    #pragma unroll
    for (int s = 128; s > 0; s >>= 1){
      if (tid < s) rs[tid] += rs[tid + s];
      __syncthreads();
    }
    if (tid == 0) rowsum[n] = rs[0];
    // permuted bf16 row: k' = t*257+f  <-  src = f*17+t ; packed ushort4 stores
    for (int i = tid; i < 1096; i += 256){
      int k0 = i*4;
      ushort4 pk;
      unsigned short v[4];
      #pragma unroll
      for (int u = 0; u < 4; u++){
        int kp = k0 + u;
        unsigned short r = 0;
        if (kp < 4369){
          int t = kp / 257, f = kp - t*257;
          r = f2bf(row[f*17 + t]);
        }
        v[u] = r;
      }
      pk.x = v[0]; pk.y = v[1]; pk.z = v[2]; pk.w = v[3];
      *(ushort4*)(Dbf + (size_t)n*4384 + k0) = pk;
    }
  } else {
    const int x = blk - 128;                  // strip 0..7
    const int w = tid >> 6, lane = tid & 63;
    const int c = lane & 15, q = lane >> 4;
    const float* arow  = D + (size_t)(x*16 + c)*4369;
    const int n0 = (2*w)*16 + c, n1 = (2*w + 1)*16 + c;
    const float* brow0 = D + (size_t)n0*4369;
    const float* brow1 = D + (size_t)n1*4369;
    f32x4 acc0 = (f32x4){0.f,0.f,0.f,0.f};
    f32x4 acc1 = (f32x4){0.f,0.f,0.f,0.f};
    for (int tt = 0; tt < 137; tt++){
      const int kb = tt*32 + q*8;
      bf16x8 af, b0, b1;
      if (tt < 136){
        #pragma unroll
        for (int j = 0; j < 8; j++){
          af[j] = (short)f2bf(arow[kb + j]);
          b0[j] = (short)f2bf(brow0[kb + j]);
          b1[j] = (short)f2bf(brow1[kb + j]);
        }
      } else {                                // tail: k in [4352,4369)
        #pragma unroll
        for (int j = 0; j < 8; j++){
          int k = kb + j;
          bool v = (k < 4369);
          af[j] = v ? (short)f2bf(arow[k])  : (short)0;
          b0[j] = v ? (short)f2bf(brow0[k]) : (short)0;
          b1[j] = v ? (short)f2bf(brow1[k]) : (short)0;
        }
      }
      acc0 = __builtin_amdgcn_mfma_f32_16x16x32_bf16(af, b0, acc0, 0, 0, 0);
      acc1 = __builtin_amdgcn_mfma_f32_16x16x32_bf16(af, b1, acc1, 0, 0, 0);
    }
    // C layout: row(q*4+r) within strip = gram row x*16+q*4+r ; col = n0/n1
    #pragma unroll
    for (int r = 0; r < 4; r++){
      int grow = x*16 + q*4 + r;
      float g0 = acc0[r] - (grow == n0 ? 1.0f : 0.0f);
      float g1 = acc1[r] - (grow == n1 ? 1.0f : 0.0f);
      gram_bf[grow*136 + n0] = f2bf(g0);
      gram_bf[grow*136 + n1] = f2bf(g1);
    }
  }
}

// ---------------- radix-8 butterfly (DIT), in registers ----------------------
__device__ __forceinline__ void dft8(float xr[8], float xi[8]){
  const float C = 0.70710678118654752f;
  float t0r = xr[0]+xr[4], t0i = xi[0]+xi[4];
  float t1r = xr[0]-xr[4], t1i = xi[0]-xi[4];
  float t2r = xr[2]+xr[6], t2i = xi[2]+xi[6];
  float t3r = xr[2]-xr[6], t3i = xi[2]-xi[6];
  float e0r = t0r+t2r, e0i = t0i+t2i;
  float e2r = t0r-t2r, e2i = t0i-t2i;
  float e1r = t1r+t3i, e1i = t1i-t3r;
  float e3r = t1r-t3i, e3i = t1i+t3r;
  float s0r = xr[1]+xr[5], s0i = xi[1]+xi[5];
  float s1r = xr[1]-xr[5], s1i = xi[1]-xi[5];
  float s2r = xr[3]+xr[7], s2i = xi[3]+xi[7];
  float s3r = xr[3]-xr[7], s3i = xi[3]-xi[7];
  float o0r = s0r+s2r, o0i = s0i+s2i;
  float o2r = s0r-s2r, o2i = s0i-s2i;
  float o1r = s1r+s3i, o1i = s1i-s3r;
  float o3r = s1r-s3i, o3i = s1i+s3r;
  xr[0] = e0r+o0r; xi[0] = e0i+o0i;
  xr[4] = e0r-o0r; xi[4] = e0i-o0i;
  float w1r = C*(o1r+o1i), w1i = C*(o1i-o1r);
  xr[1] = e1r+w1r; xi[1] = e1i+w1i;
  xr[5] = e1r-w1r; xi[5] = e1i-w1i;
  xr[2] = e2r+o2i; xi[2] = e2i-o2r;
  xr[6] = e2r-o2i; xi[6] = e2i+o2r;
  float w3r = C*(o3i-o3r), w3i = -C*(o3r+o3i);
  xr[3] = e3r+w3r; xi[3] = e3i+w3i;
  xr[7] = e3r-w3r; xi[7] = e3i-w3i;
}

// ---------------- K1: STFT magnitude + per-frame moment partials -------------
// 4 waves/WG, each wave = one FRAME PAIR packed a+ib; private LDS Z slice;
// zero barriers. Twiddles: 2 transcendentals/stage + complex-mul recurrence.
// Epilogue: s1/s2 per frame on fp32 magnitudes (pre-bf16), shfl-reduced,
// one float4 store per pair -> psf[frame][2] = {s1, s2}.
__global__ __launch_bounds__(256) void k_stft(const float* __restrict__ audio,
    unsigned short* __restrict__ spec, float* __restrict__ psf){
  __shared__ float2 zb[4][616];
  const int tid = threadIdx.x;
  const int wid = tid >> 6;
  const int L = tid & 63;
  float2* Z = zb[wid];
  const int pair = blockIdx.x*4 + wid;        // 0..69631
  const int fr0 = pair*2;
  const int b0 = fr0/17, t0 = fr0 - b0*17;
  const int fr1 = fr0 + 1;
  const int b1 = fr1/17, t1 = fr1 - b1*17;
  const float* sA = audio + (size_t)b0*3200 + t0*160;
  const float* sB = audio + (size_t)b1*3200 + t1*160;
  float xr[8], xi[8];
  // fused digit-reversed load + window; idx=8L+e -> r9 = baseRev+64e.
  // window w(r9) = 0.5 - 0.5 cos(th0 + e*pi/4): rotor recurrence, 2 transcendentals.
  {
    const int baseRev = ((L & 7) << 3) | (L >> 3);
    float th0 = (float)baseRev * TWO_PI_OVER_512;
    float cw = __cosf(th0), sw = __sinf(th0);
    #pragma unroll
    for (int e = 0; e < 8; e++){
      int r9 = baseRev + (e << 6);
      float w = 0.5f - 0.5f*cw;
      xr[e] = sA[r9]*w;
      xi[e] = sB[r9]*w;
      float nc = C8*(cw - sw), ns = C8*(sw + cw);  // rotate by pi/4
      cw = nc; sw = ns;
    }
  }
  dft8(xr, xi);
  {
    int s0 = 9*L + 5*(L >> 3);                // slot(8L), e contiguous
    #pragma unroll
    for (int e = 0; e < 8; e++) Z[s0 + e] = make_float2(xr[e], xi[e]);
  }
  // stage 1: i = g*64 + j + 8e -> slot = 77g + j + 9e ; W_64^{je} via rotor chain
  {
    int j = L & 7, g = L >> 3;
    int sb = 77*g + j;
    #pragma unroll
    for (int e = 0; e < 8; e++){
      float2 z = Z[sb + 9*e];
      xr[e] = z.x; xi[e] = z.y;
    }
    float ang = (float)j * TWO_PI_OVER_64;
    float c1 = __cosf(ang), s1 = __sinf(ang); // W = c - i s
    float cw = c1, sw = s1;
    #pragma unroll
    for (int e = 1; e < 8; e++){
      float a = xr[e], b = xi[e];
      xr[e] = a*cw + b*sw;
      xi[e] = b*cw - a*sw;
      float nc = cw*c1 - sw*s1, ns = sw*c1 + cw*s1;
      cw = nc; sw = ns;
    }
    dft8(xr, xi);
    #pragma unroll
    for (int e = 0; e < 8; e++) Z[sb + 9*e] = make_float2(xr[e], xi[e]);
  }
  // stage 2: i = L + 64e -> slot = L + (L>>3) + 77e ; lane L ends with Z[k=L+64f]
  {
    int sb = L + (L >> 3);
    #pragma unroll
    for (int e = 0; e < 8; e++){
      float2 z = Z[sb + 77*e];
      xr[e] = z.x; xi[e] = z.y;
    }
    float ang = (float)L * TWO_PI_OVER_512;
    float c1 = __cosf(ang), s1 = __sinf(ang);
    float cw = c1, sw = s1;
    #pragma unroll
    for (int e = 1; e < 8; e++){
      float a = xr[e], b = xi[e];
      xr[e] = a*cw + b*sw;
      xi[e] = b*cw - a*sw;
      float nc = cw*c1 - sw*s1, ns = sw*c1 + cw*s1;
      cw = nc; sw = ns;
    }
    dft8(xr, xi);
  }
  // conj-partner exchange: partner of k=L+64f is lane (64-L)&63, reg 7-f (L>=1)
  float pr[4], pi[4];
  {
    const int partner = (64 - L) & 63;
    #pragma unroll
    for (int f = 0; f < 4; f++){
      pr[f] = __shfl(xr[7-f], partner);
      pi[f] = __shfl(xi[7-f], partner);
    }
    if (L == 0){                              // lane 0: partner regs are own (8-f)&7
      pr[0] = xr[0]; pi[0] = xi[0];
      pr[1] = xr[7]; pi[1] = xi[7];
      pr[2] = xr[6]; pi[2] = xi[6];
      pr[3] = xr[5]; pi[3] = xi[5];
    }
  }
  unsigned short* dA = spec + (size_t)b0*4384 + t0*257;
  unsigned short* dB = spec + (size_t)b1*4384 + t1*257;
  float s1A = 0.f, s2A = 0.f, s1B = 0.f, s2B = 0.f;
  #pragma unroll
  for (int f = 0; f < 4; f++){
    int k = L + 64*f;
    float ar = xr[f] + pr[f], ai = xi[f] - pi[f];
    float br = xi[f] + pi[f], bi = pr[f] - xr[f];
    float mA = 0.5f*sqrtf(ar*ar + ai*ai);
    float mB = 0.5f*sqrtf(br*br + bi*bi);
    dA[k] = f2bf(mA);
    dB[k] = f2bf(mB);
    s1A += mA; s2A = fmaf(mA, mA, s2A);
    s1B += mB; s2B = fmaf(mB, mB, s2B);
  }
  if (L == 0){                                // k=256: Xa=Re(Z[256]), Xb=Im(Z[256])
    float mA = fabsf(xr[4]), mB = fabsf(xi[4]);
    dA[256] = f2bf(mA);
    dB[256] = f2bf(mB);
    s1A += mA; s2A = fmaf(mA, mA, s2A);
    s1B += mB; s2B = fmaf(mB, mB, s2B);
  }
  #pragma unroll
  for (int off = 32; off > 0; off >>= 1){
    s1A += __shfl_xor(s1A, off);
    s2A += __shfl_xor(s2A, off);
    s1B += __shfl_xor(s1B, off);
    s2B += __shfl_xor(s2B, off);
  }
  if (L == 0)
    *(float4*)(psf + (size_t)fr0*2) = make_float4(s1A, s2A, s1B, s2B);
  if (t0 == 0 && L < 15) spec[(size_t)b0*4384 + 4369 + L] = 0;
  if (t1 == 0 && L < 15) spec[(size_t)b1*4384 + 4369 + L] = 0;
}

// ---------------- K4: partial GEMM spec·Dᵀ, M=32/wave, K-split 8 -------------
// grid (128, 8), 128 thr (2 waves). Wave handles rows [mbase, mbase+32):
// 2 A-frags x 8 B-frags = 16 MFMAs per 10 loads per k-step.
__global__ __launch_bounds__(128) void k_gemm(const unsigned short* __restrict__ spec,
    const unsigned short* __restrict__ Dbf, float* __restrict__ part){
  const int mtile = blockIdx.x;               // 0..127 (64 rows per WG)
  const int ks = blockIdx.y;                  // 0..7
  const int wv = threadIdx.x >> 6;
  const int lane = threadIdx.x & 63;
  const int c = lane & 15, q = lane >> 4;
  const int mbase = mtile*64 + wv*32;
  const unsigned short* ap0 = spec + (size_t)(mbase + c)*4384 + q*8;
  const unsigned short* ap1 = ap0 + (size_t)16*4384;
  const unsigned short* bp  = Dbf + (size_t)c*4384 + q*8;
  const int t0 = ks*17, t1 = (ks == 7) ? 137 : t0 + 17;
  f32x4 acc[2][8];
  #pragma unroll
  for (int ar = 0; ar < 2; ar++)
    #pragma unroll
    for (int nt = 0; nt < 8; nt++) acc[ar][nt] = (f32x4){0.f,0.f,0.f,0.f};
  int k0 = t0*32;
  bf16x8 aC0 = *(const bf16x8*)(ap0 + k0);
  bf16x8 aC1 = *(const bf16x8*)(ap1 + k0);
  bf16x8 bC[8];
  #pragma unroll
  for (int nt = 0; nt < 8; nt++)
    bC[nt] = *(const bf16x8*)(bp + (size_t)nt*16*4384 + k0);
  for (int tt = t0; tt < t1; tt++){
    const int tn = (tt + 1 < t1) ? tt + 1 : tt;
    const int kn = tn*32;
    bf16x8 aN0 = *(const bf16x8*)(ap0 + kn);
    bf16x8 aN1 = *(const bf16x8*)(ap1 + kn);
    bf16x8 bN[8];
    #pragma unroll
    for (int nt = 0; nt < 8; nt++)
      bN[nt] = *(const bf16x8*)(bp + (size_t)nt*16*4384 + kn);
    #pragma unroll
    for (int nt = 0; nt < 8; nt++){
      acc[0][nt] = __builtin_amdgcn_mfma_f32_16x16x32_bf16(aC0, bC[nt], acc[0][nt], 0, 0, 0);
      acc[1][nt] = __builtin_amdgcn_mfma_f32_16x16x32_bf16(aC1, bC[nt], acc[1][nt], 0, 0, 0);
    }
    aC0 = aN0; aC1 = aN1;
    #pragma unroll
    for (int nt = 0; nt < 8; nt++) bC[nt] = bN[nt];
  }
  // part[ks][n][m]: n = nt*16+c, m = mbase + ar*16 + q*4 + r
  #pragma unroll
  for (int nt = 0; nt < 8; nt++){
    float* b0 = part + ((size_t)(ks*128 + nt*16 + c))*8192 + mbase + q*4;
    *(f32x4*)(b0)      = acc[0][nt];
    *(f32x4*)(b0 + 16) = acc[1][nt];
  }
}

// ---------------- K5: LCA, 50 iters. rᵀ = G·aᵀ; 4 waves x 32 gram rows ------
// 512 blocks x 256 thr: block = 16 samples; wave wv owns rows [wv*32, wv*32+32).
// a exchanged via double-buffered LDS, ONE barrier per iter.
__global__ __launch_bounds__(256) void k_lca(const float* __restrict__ part,
    const unsigned short* __restrict__ gram_bf, const float* __restrict__ rowsum,
    const float* __restrict__ psf, float* __restrict__ out){
  __shared__ unsigned short A[2][16*136];
  const int tid = threadIdx.x, wv = tid >> 6, lane = tid & 63;
  const int c = lane & 15, q = lane >> 4;
  const int sg = blockIdx.x*16 + c;
  // moments: sum 17 per-frame (s1,s2) pairs (fp32, fixed order)
  const float* pf = psf + (size_t)sg*34;
  float S1 = 0.f, S2 = 0.f;
  #pragma unroll
  for (int t = 0; t < 17; t++){
    S1 += pf[2*t];
    S2 += pf[2*t + 1];
  }
  const float mus = S1 / 4369.0f;
  float var = (S2 - S1*S1/4369.0f) / 4368.0f;
  var = fmaxf(var, 0.0f);
  const float invs = 1.0f / (sqrtf(var) + 1e-8f);
  const int nb = wv*32;
  bf16x8 Gf[2][4];                            // A-frags of G rows [nb, nb+32)
  #pragma unroll
  for (int rt = 0; rt < 2; rt++)
    #pragma unroll
    for (int kt = 0; kt < 4; kt++)
      Gf[rt][kt] = *(const bf16x8*)(gram_bf + (size_t)(nb + rt*16 + c)*136 + kt*32 + q*8);
  f32x4 U[2], Bb[2];
  #pragma unroll
  for (int rt = 0; rt < 2; rt++){
    #pragma unroll
    for (int r = 0; r < 4; r++){
      int n = nb + rt*16 + q*4 + r;
      float S = 0.f;
      #pragma unroll
      for (int s = 0; s < 8; s++)
        S += part[((size_t)(s*128 + n))*8192 + sg];
      Bb[rt][r] = invs * (S - mus * rowsum[n]);
      U[rt][r] = 0.0f;
    }
  }
  for (int it = 0; it < 50; it++){
    unsigned short* Ab = A[it & 1];
    #pragma unroll
    for (int rt = 0; rt < 2; rt++){
      ushort4 pk;
      pk.x = f2bf(sshrink(U[rt][0]));
      pk.y = f2bf(sshrink(U[rt][1]));
      pk.z = f2bf(sshrink(U[rt][2]));
      pk.w = f2bf(sshrink(U[rt][3]));
      *(ushort4*)(Ab + c*136 + nb + rt*16 + q*4) = pk;
    }
    __syncthreads();
    bf16x8 af[4];
    #pragma unroll
    for (int kt = 0; kt < 4; kt++)            // B-frag: aᵀ[k][sample=c]
      af[kt] = *(const bf16x8*)(Ab + c*136 + kt*32 + q*8);
    f32x4 R[2];
    R[0] = (f32x4){0.f,0.f,0.f,0.f};
    R[1] = (f32x4){0.f,0.f,0.f,0.f};
    #pragma unroll
    for (int kt = 0; kt < 4; kt++)            // kt outer: R[0],R[1] chains interleave
      #pragma unroll
      for (int rt = 0; rt < 2; rt++)
        R[rt] = __builtin_amdgcn_mfma_f32_16x16x32_bf16(Gf[rt][kt], af[kt], R[rt], 0, 0, 0);
    #pragma unroll
    for (int rt = 0; rt < 2; rt++){
      #pragma unroll
      for (int r = 0; r < 4; r++){
        float u = U[rt][r];
        U[rt][r] = u + (Bb[rt][r] - u - R[rt][r]) * 0.1f;
      }
    }
  }
  #pragma unroll
  for (int rt = 0; rt < 2; rt++){
    float4 o;
    o.x = sshrink(U[rt][0]);
    o.y = sshrink(U[rt][1]);
    o.z = sshrink(U[rt][2]);
    o.w = sshrink(U[rt][3]);
    *(float4*)(out + (size_t)sg*128 + nb + rt*16 + q*4) = o;
  }
}

// ---------------- launch ----------------
extern "C" void kernel_launch(void* const* d_in, const int* in_sizes, int n_in,
                              void* d_out, int out_size, void* d_ws, size_t ws_size,
                              hipStream_t stream){
  const float* audio = (const float*)d_in[0];   // 8192*3200
  const float* D     = (const float*)d_in[1];   // 128*4369
  float* out = (float*)d_out;                   // 8192*128 f32
  char* ws = (char*)d_ws;
  // workspace layout, total ~107.7 MB
  unsigned short* spec   = (unsigned short*)(ws);               // 71,827,456
  float*          part   = (float*)(ws + 71827456);             // 33,554,432 (8 slices)
  unsigned short* Dbf    = (unsigned short*)(ws + 105381888);   // 1,122,304
  unsigned short* gram   = (unsigned short*)(ws + 106504192);   // 34,816
  float*          rowsum = (float*)(ws + 106539008);            // 512
  float*          psf    = (float*)(ws + 106539520);            // 1,114,112 (8192*17*2)

  k_stft <<<17408, 256, 0, stream>>>(audio, spec, psf);
  k_prep <<<136, 256, 0, stream>>>(D, Dbf, rowsum, gram);
  k_gemm <<<dim3(128, 8, 1), 128, 0, stream>>>(spec, Dbf, part);
  k_lca  <<<512, 256, 0, stream>>>(part, gram, rowsum, psf, out);
}

// Round 7
// 317.429 us; speedup vs baseline: 1.0549x; 1.0549x over previous
//
#include <hip/hip_runtime.h>
#include <hip/hip_bf16.h>
#include <math.h>

// A1SparseCoding: STFT(512,160,hann,center=False) -> |.| -> per-sample norm ->
// LCA (50 iters, lam=0.5, tau=10) -> softshrink(u)
// B=8192, SEG=3200, T=17 frames, F=257 freqs, K=17*257=4369 (pad 4384), N=128 bases.
// spec stored [b][t*257+f]; D's columns permuted identically (dot products invariant).
// STFT: two real frames packed as one complex FFT (a+ib), radix-8 DIT, fp32,
// rotor-recurrence twiddles (R0 form; table variants R2/R3 latency-bound, reverted).
// R4: per-frame moments fused into k_stft epilogue; k_gemm M=32/wave K-split 8.
// R5 finding: harness re-poison = 2x 400MiB fill ~120us inside the timed iter;
// launch boundary ~5-7us.
// R6 failure: k_prep gram read RAW D (rows 17476B = not 16B aligned) -> 24 scalar
// loads/iter, ~16-32 cache lines per instr, 1 wave/SIMD, latency-bound +45us.
// R7: 3 launches, all fused blocks use vectorized loads:
//   k_stft grid 17536 = 17408 stft blocks + 128 dprep blocks (coalesced D reads);
//   k_gemm grid (128,9): y==8 -> 8 gram blocks reading Dbf via b128 (16B aligned),
//   full-K ascending order -> exactly symmetric gram, written directly.

typedef short bf16x8 __attribute__((ext_vector_type(8)));
typedef float f32x4  __attribute__((ext_vector_type(4)));

#define TWO_PI_OVER_512 0.01227184630f
#define TWO_PI_OVER_64  0.09817477042f
#define C8 0.70710678118654752f

__device__ __forceinline__ unsigned short f2bf(float f){
  unsigned int u = __float_as_uint(f);
  u += 0x7FFFu + ((u >> 16) & 1u);      // RNE; inputs finite
  return (unsigned short)(u >> 16);
}
__device__ __forceinline__ float sshrink(float u){
  float a = fabsf(u) - 0.5f;
  return a > 0.0f ? copysignf(a, u) : 0.0f;
}

// ---------------- radix-8 butterfly (DIT), in registers ----------------------
__device__ __forceinline__ void dft8(float xr[8], float xi[8]){
  const float C = 0.70710678118654752f;
  float t0r = xr[0]+xr[4], t0i = xi[0]+xi[4];
  float t1r = xr[0]-xr[4], t1i = xi[0]-xi[4];
  float t2r = xr[2]+xr[6], t2i = xi[2]+xi[6];
  float t3r = xr[2]-xr[6], t3i = xi[2]-xi[6];
  float e0r = t0r+t2r, e0i = t0i+t2i;
  float e2r = t0r-t2r, e2i = t0i-t2i;
  float e1r = t1r+t3i, e1i = t1i-t3r;
  float e3r = t1r-t3i, e3i = t1i+t3r;
  float s0r = xr[1]+xr[5], s0i = xi[1]+xi[5];
  float s1r = xr[1]-xr[5], s1i = xi[1]-xi[5];
  float s2r = xr[3]+xr[7], s2i = xi[3]+xi[7];
  float s3r = xr[3]-xr[7], s3i = xi[3]-xi[7];
  float o0r = s0r+s2r, o0i = s0i+s2i;
  float o2r = s0r-s2r, o2i = s0i-s2i;
  float o1r = s1r+s3i, o1i = s1i-s3r;
  float o3r = s1r-s3i, o3i = s1i+s3r;
  xr[0] = e0r+o0r; xi[0] = e0i+o0i;
  xr[4] = e0r-o0r; xi[4] = e0i-o0i;
  float w1r = C*(o1r+o1i), w1i = C*(o1i-o1r);
  xr[1] = e1r+w1r; xi[1] = e1i+w1i;
  xr[5] = e1r-w1r; xi[5] = e1i-w1i;
  xr[2] = e2r+o2i; xi[2] = e2i-o2r;
  xr[6] = e2r-o2i; xi[6] = e2i+o2r;
  float w3r = C*(o3i-o3r), w3i = -C*(o3r+o3i);
  xr[3] = e3r+w3r; xi[3] = e3i+w3i;
  xr[7] = e3r-w3r; xi[7] = e3i-w3i;
}

// ---------------- K1: STFT magnitude + moments ‖ D-prep (fused) --------------
// blocks 0..17407: STFT. 4 waves/WG, each wave = one FRAME PAIR packed a+ib;
//   private LDS Z slice; zero barriers; rotor twiddles; epilogue computes
//   per-frame s1/s2 on fp32 magnitudes (shfl-reduce, float4 store per pair).
// blocks 17408..17535: D prep row n = blk-17408 (coalesced fp32 reads, LDS
//   permute k'=t*257+f <- f*17+t, bf16 pack, rowsum). LDS union with Z.
__global__ __launch_bounds__(256) void k_stft(const float* __restrict__ audio,
    const float* __restrict__ D, unsigned short* __restrict__ spec,
    float* __restrict__ psf, unsigned short* __restrict__ Dbf,
    float* __restrict__ rowsum){
  __shared__ __align__(16) char smraw[19712];   // max(4*616*8, 4369*4+256*4)
  const int tid = threadIdx.x;
  const int blk = blockIdx.x;
  if (blk >= 17408){
    // ---- D-prep branch ----
    float* row = (float*)smraw;                 // [4369]
    float* rs  = (float*)(smraw + 17476);       // [256]
    const int n = blk - 17408;
    float acc = 0.0f;
    for (int k = tid; k < 4369; k += 256){
      float v = D[(size_t)n*4369 + k];          // coalesced
      row[k] = v;
      acc += v;
    }
    rs[tid] = acc;
    __syncthreads();
    #pragma unroll
    for (int s = 128; s > 0; s >>= 1){
      if (tid < s) rs[tid] += rs[tid + s];
      __syncthreads();
    }
    if (tid == 0) rowsum[n] = rs[0];
    for (int i = tid; i < 1096; i += 256){
      int k0 = i*4;
      ushort4 pk;
      unsigned short v[4];
      #pragma unroll
      for (int u = 0; u < 4; u++){
        int kp = k0 + u;
        unsigned short r = 0;
        if (kp < 4369){
          int t = kp / 257, f = kp - t*257;
          r = f2bf(row[f*17 + t]);
        }
        v[u] = r;
      }
      pk.x = v[0]; pk.y = v[1]; pk.z = v[2]; pk.w = v[3];
      *(ushort4*)(Dbf + (size_t)n*4384 + k0) = pk;
    }
    return;
  }
  // ---- STFT branch ----
  float2 (*zb)[616] = (float2(*)[616])smraw;
  const int wid = tid >> 6;
  const int L = tid & 63;
  float2* Z = zb[wid];
  const int pair = blk*4 + wid;               // 0..69631
  const int fr0 = pair*2;
  const int b0 = fr0/17, t0 = fr0 - b0*17;
  const int fr1 = fr0 + 1;
  const int b1 = fr1/17, t1 = fr1 - b1*17;
  const float* sA = audio + (size_t)b0*3200 + t0*160;
  const float* sB = audio + (size_t)b1*3200 + t1*160;
  float xr[8], xi[8];
  // fused digit-reversed load + window; idx=8L+e -> r9 = baseRev+64e.
  // window w(r9) = 0.5 - 0.5 cos(th0 + e*pi/4): rotor recurrence, 2 transcendentals.
  {
    const int baseRev = ((L & 7) << 3) | (L >> 3);
    float th0 = (float)baseRev * TWO_PI_OVER_512;
    float cw = __cosf(th0), sw = __sinf(th0);
    #pragma unroll
    for (int e = 0; e < 8; e++){
      int r9 = baseRev + (e << 6);
      float w = 0.5f - 0.5f*cw;
      xr[e] = sA[r9]*w;
      xi[e] = sB[r9]*w;
      float nc = C8*(cw - sw), ns = C8*(sw + cw);  // rotate by pi/4
      cw = nc; sw = ns;
    }
  }
  dft8(xr, xi);
  {
    int s0 = 9*L + 5*(L >> 3);                // slot(8L), e contiguous
    #pragma unroll
    for (int e = 0; e < 8; e++) Z[s0 + e] = make_float2(xr[e], xi[e]);
  }
  // stage 1: i = g*64 + j + 8e -> slot = 77g + j + 9e ; W_64^{je} via rotor chain
  {
    int j = L & 7, g = L >> 3;
    int sb = 77*g + j;
    #pragma unroll
    for (int e = 0; e < 8; e++){
      float2 z = Z[sb + 9*e];
      xr[e] = z.x; xi[e] = z.y;
    }
    float ang = (float)j * TWO_PI_OVER_64;
    float c1 = __cosf(ang), s1 = __sinf(ang); // W = c - i s
    float cw = c1, sw = s1;
    #pragma unroll
    for (int e = 1; e < 8; e++){
      float a = xr[e], b = xi[e];
      xr[e] = a*cw + b*sw;
      xi[e] = b*cw - a*sw;
      float nc = cw*c1 - sw*s1, ns = sw*c1 + cw*s1;
      cw = nc; sw = ns;
    }
    dft8(xr, xi);
    #pragma unroll
    for (int e = 0; e < 8; e++) Z[sb + 9*e] = make_float2(xr[e], xi[e]);
  }
  // stage 2: i = L + 64e -> slot = L + (L>>3) + 77e ; lane L ends with Z[k=L+64f]
  {
    int sb = L + (L >> 3);
    #pragma unroll
    for (int e = 0; e < 8; e++){
      float2 z = Z[sb + 77*e];
      xr[e] = z.x; xi[e] = z.y;
    }
    float ang = (float)L * TWO_PI_OVER_512;
    float c1 = __cosf(ang), s1 = __sinf(ang);
    float cw = c1, sw = s1;
    #pragma unroll
    for (int e = 1; e < 8; e++){
      float a = xr[e], b = xi[e];
      xr[e] = a*cw + b*sw;
      xi[e] = b*cw - a*sw;
      float nc = cw*c1 - sw*s1, ns = sw*c1 + cw*s1;
      cw = nc; sw = ns;
    }
    dft8(xr, xi);
  }
  // conj-partner exchange: partner of k=L+64f is lane (64-L)&63, reg 7-f (L>=1)
  float pr[4], pi[4];
  {
    const int partner = (64 - L) & 63;
    #pragma unroll
    for (int f = 0; f < 4; f++){
      pr[f] = __shfl(xr[7-f], partner);
      pi[f] = __shfl(xi[7-f], partner);
    }
    if (L == 0){                              // lane 0: partner regs are own (8-f)&7
      pr[0] = xr[0]; pi[0] = xi[0];
      pr[1] = xr[7]; pi[1] = xi[7];
      pr[2] = xr[6]; pi[2] = xi[6];
      pr[3] = xr[5]; pi[3] = xi[5];
    }
  }
  unsigned short* dA = spec + (size_t)b0*4384 + t0*257;
  unsigned short* dB = spec + (size_t)b1*4384 + t1*257;
  float s1A = 0.f, s2A = 0.f, s1B = 0.f, s2B = 0.f;
  #pragma unroll
  for (int f = 0; f < 4; f++){
    int k = L + 64*f;
    float ar = xr[f] + pr[f], ai = xi[f] - pi[f];
    float br = xi[f] + pi[f], bi = pr[f] - xr[f];
    float mA = 0.5f*sqrtf(ar*ar + ai*ai);
    float mB = 0.5f*sqrtf(br*br + bi*bi);
    dA[k] = f2bf(mA);
    dB[k] = f2bf(mB);
    s1A += mA; s2A = fmaf(mA, mA, s2A);
    s1B += mB; s2B = fmaf(mB, mB, s2B);
  }
  if (L == 0){                                // k=256: Xa=Re(Z[256]), Xb=Im(Z[256])
    float mA = fabsf(xr[4]), mB = fabsf(xi[4]);
    dA[256] = f2bf(mA);
    dB[256] = f2bf(mB);
    s1A += mA; s2A = fmaf(mA, mA, s2A);
    s1B += mB; s2B = fmaf(mB, mB, s2B);
  }
  #pragma unroll
  for (int off = 32; off > 0; off >>= 1){
    s1A += __shfl_xor(s1A, off);
    s2A += __shfl_xor(s2A, off);
    s1B += __shfl_xor(s1B, off);
    s2B += __shfl_xor(s2B, off);
  }
  if (L == 0)
    *(float4*)(psf + (size_t)fr0*2) = make_float4(s1A, s2A, s1B, s2B);
  if (t0 == 0 && L < 15) spec[(size_t)b0*4384 + 4369 + L] = 0;
  if (t1 == 0 && L < 15) spec[(size_t)b1*4384 + 4369 + L] = 0;
}

// ---------------- K4: partial GEMM spec·Dᵀ ‖ gram (fused) --------------------
// grid (128, 9), 128 thr (2 waves).
// y<8: GEMM k-slice. Wave handles rows [mbase, mbase+32): 2 A-frags x 8 B-frags
//   = 16 MFMAs per 10 loads per k-step.
// y==8, x<8: gram strip x (16x128) from Dbf (16B-aligned b128 loads), full-K
//   ascending order -> exactly symmetric; writes gram_bf (minus eye) directly.
__global__ __launch_bounds__(128) void k_gemm(const unsigned short* __restrict__ spec,
    const unsigned short* __restrict__ Dbf, float* __restrict__ part,
    unsigned short* __restrict__ gram_bf){
  if (blockIdx.y == 8){
    if (blockIdx.x >= 8) return;
    const int x = blockIdx.x;                 // strip 0..7
    const int gw = threadIdx.x >> 6, glane = threadIdx.x & 63;
    const int gc = glane & 15, gq = glane >> 4;
    const unsigned short* gap = Dbf + (size_t)(x*16 + gc)*4384 + gq*8;
    f32x4 gacc[4];
    #pragma unroll
    for (int i = 0; i < 4; i++) gacc[i] = (f32x4){0.f,0.f,0.f,0.f};
    for (int tt = 0; tt < 137; tt++){
      const int k0 = tt*32;
      bf16x8 af = *(const bf16x8*)(gap + k0);
      #pragma unroll
      for (int i = 0; i < 4; i++){
        int nt = gw*4 + i;
        bf16x8 bfr = *(const bf16x8*)(Dbf + (size_t)(nt*16 + gc)*4384 + gq*8 + k0);
        gacc[i] = __builtin_amdgcn_mfma_f32_16x16x32_bf16(af, bfr, gacc[i], 0, 0, 0);
      }
    }
    // C layout: gram row = x*16 + gq*4 + r, col = nt*16 + gc
    #pragma unroll
    for (int i = 0; i < 4; i++){
      int nt = gw*4 + i;
      #pragma unroll
      for (int r = 0; r < 4; r++){
        int grow = x*16 + gq*4 + r;
        int gcol = nt*16 + gc;
        float g = gacc[i][r] - (grow == gcol ? 1.0f : 0.0f);
        gram_bf[grow*136 + gcol] = f2bf(g);
      }
    }
    return;
  }
  const int mtile = blockIdx.x;               // 0..127 (64 rows per WG)
  const int ks = blockIdx.y;                  // 0..7
  const int wv = threadIdx.x >> 6;
  const int lane = threadIdx.x & 63;
  const int c = lane & 15, q = lane >> 4;
  const int mbase = mtile*64 + wv*32;
  const unsigned short* ap0 = spec + (size_t)(mbase + c)*4384 + q*8;
  const unsigned short* ap1 = ap0 + (size_t)16*4384;
  const unsigned short* bp  = Dbf + (size_t)c*4384 + q*8;
  const int t0 = ks*17, t1 = (ks == 7) ? 137 : t0 + 17;
  f32x4 acc[2][8];
  #pragma unroll
  for (int ar = 0; ar < 2; ar++)
    #pragma unroll
    for (int nt = 0; nt < 8; nt++) acc[ar][nt] = (f32x4){0.f,0.f,0.f,0.f};
  int k0 = t0*32;
  bf16x8 aC0 = *(const bf16x8*)(ap0 + k0);
  bf16x8 aC1 = *(const bf16x8*)(ap1 + k0);
  bf16x8 bC[8];
  #pragma unroll
  for (int nt = 0; nt < 8; nt++)
    bC[nt] = *(const bf16x8*)(bp + (size_t)nt*16*4384 + k0);
  for (int tt = t0; tt < t1; tt++){
    const int tn = (tt + 1 < t1) ? tt + 1 : tt;
    const int kn = tn*32;
    bf16x8 aN0 = *(const bf16x8*)(ap0 + kn);
    bf16x8 aN1 = *(const bf16x8*)(ap1 + kn);
    bf16x8 bN[8];
    #pragma unroll
    for (int nt = 0; nt < 8; nt++)
      bN[nt] = *(const bf16x8*)(bp + (size_t)nt*16*4384 + kn);
    #pragma unroll
    for (int nt = 0; nt < 8; nt++){
      acc[0][nt] = __builtin_amdgcn_mfma_f32_16x16x32_bf16(aC0, bC[nt], acc[0][nt], 0, 0, 0);
      acc[1][nt] = __builtin_amdgcn_mfma_f32_16x16x32_bf16(aC1, bC[nt], acc[1][nt], 0, 0, 0);
    }
    aC0 = aN0; aC1 = aN1;
    #pragma unroll
    for (int nt = 0; nt < 8; nt++) bC[nt] = bN[nt];
  }
  // part[ks][n][m]: n = nt*16+c, m = mbase + ar*16 + q*4 + r
  #pragma unroll
  for (int nt = 0; nt < 8; nt++){
    float* b0 = part + ((size_t)(ks*128 + nt*16 + c))*8192 + mbase + q*4;
    *(f32x4*)(b0)      = acc[0][nt];
    *(f32x4*)(b0 + 16) = acc[1][nt];
  }
}

// ---------------- K5: LCA, 50 iters. rᵀ = G·aᵀ; 4 waves x 32 gram rows ------
// 512 blocks x 256 thr: block = 16 samples; wave wv owns rows [wv*32, wv*32+32).
// a exchanged via double-buffered LDS, ONE barrier per iter.
__global__ __launch_bounds__(256) void k_lca(const float* __restrict__ part,
    const unsigned short* __restrict__ gram_bf, const float* __restrict__ rowsum,
    const float* __restrict__ psf, float* __restrict__ out){
  __shared__ unsigned short A[2][16*136];
  const int tid = threadIdx.x, wv = tid >> 6, lane = tid & 63;
  const int c = lane & 15, q = lane >> 4;
  const int sg = blockIdx.x*16 + c;
  // moments: sum 17 per-frame (s1,s2) pairs (fp32, fixed order)
  const float* pf = psf + (size_t)sg*34;
  float S1 = 0.f, S2 = 0.f;
  #pragma unroll
  for (int t = 0; t < 17; t++){
    S1 += pf[2*t];
    S2 += pf[2*t + 1];
  }
  const float mus = S1 / 4369.0f;
  float var = (S2 - S1*S1/4369.0f) / 4368.0f;
  var = fmaxf(var, 0.0f);
  const float invs = 1.0f / (sqrtf(var) + 1e-8f);
  const int nb = wv*32;
  bf16x8 Gf[2][4];                            // A-frags of G rows [nb, nb+32)
  #pragma unroll
  for (int rt = 0; rt < 2; rt++)
    #pragma unroll
    for (int kt = 0; kt < 4; kt++)
      Gf[rt][kt] = *(const bf16x8*)(gram_bf + (size_t)(nb + rt*16 + c)*136 + kt*32 + q*8);
  f32x4 U[2], Bb[2];
  #pragma unroll
  for (int rt = 0; rt < 2; rt++){
    #pragma unroll
    for (int r = 0; r < 4; r++){
      int n = nb + rt*16 + q*4 + r;
      float S = 0.f;
      #pragma unroll
      for (int s = 0; s < 8; s++)
        S += part[((size_t)(s*128 + n))*8192 + sg];
      Bb[rt][r] = invs * (S - mus * rowsum[n]);
      U[rt][r] = 0.0f;
    }
  }
  for (int it = 0; it < 50; it++){
    unsigned short* Ab = A[it & 1];
    #pragma unroll
    for (int rt = 0; rt < 2; rt++){
      ushort4 pk;
      pk.x = f2bf(sshrink(U[rt][0]));
      pk.y = f2bf(sshrink(U[rt][1]));
      pk.z = f2bf(sshrink(U[rt][2]));
      pk.w = f2bf(sshrink(U[rt][3]));
      *(ushort4*)(Ab + c*136 + nb + rt*16 + q*4) = pk;
    }
    __syncthreads();
    bf16x8 af[4];
    #pragma unroll
    for (int kt = 0; kt < 4; kt++)            // B-frag: aᵀ[k][sample=c]
      af[kt] = *(const bf16x8*)(Ab + c*136 + kt*32 + q*8);
    f32x4 R[2];
    R[0] = (f32x4){0.f,0.f,0.f,0.f};
    R[1] = (f32x4){0.f,0.f,0.f,0.f};
    #pragma unroll
    for (int kt = 0; kt < 4; kt++)            // kt outer: R[0],R[1] chains interleave
      #pragma unroll
      for (int rt = 0; rt < 2; rt++)
        R[rt] = __builtin_amdgcn_mfma_f32_16x16x32_bf16(Gf[rt][kt], af[kt], R[rt], 0, 0, 0);
    #pragma unroll
    for (int rt = 0; rt < 2; rt++){
      #pragma unroll
      for (int r = 0; r < 4; r++){
        float u = U[rt][r];
        U[rt][r] = u + (Bb[rt][r] - u - R[rt][r]) * 0.1f;
      }
    }
  }
  #pragma unroll
  for (int rt = 0; rt < 2; rt++){
    float4 o;
    o.x = sshrink(U[rt][0]);
    o.y = sshrink(U[rt][1]);
    o.z = sshrink(U[rt][2]);
    o.w = sshrink(U[rt][3]);
    *(float4*)(out + (size_t)sg*128 + nb + rt*16 + q*4) = o;
  }
}

// ---------------- launch ----------------
extern "C" void kernel_launch(void* const* d_in, const int* in_sizes, int n_in,
                              void* d_out, int out_size, void* d_ws, size_t ws_size,
                              hipStream_t stream){
  const float* audio = (const float*)d_in[0];   // 8192*3200
  const float* D     = (const float*)d_in[1];   // 128*4369
  float* out = (float*)d_out;                   // 8192*128 f32
  char* ws = (char*)d_ws;
  // workspace layout, total ~107.7 MB
  unsigned short* spec   = (unsigned short*)(ws);               // 71,827,456
  float*          part   = (float*)(ws + 71827456);             // 33,554,432 (8 slices)
  unsigned short* Dbf    = (unsigned short*)(ws + 105381888);   // 1,122,304
  unsigned short* gram   = (unsigned short*)(ws + 106504192);   // 34,816
  float*          rowsum = (float*)(ws + 106539008);            // 512
  float*          psf    = (float*)(ws + 106539520);            // 1,114,112 (8192*17*2)

  k_stft <<<17536, 256, 0, stream>>>(audio, D, spec, psf, Dbf, rowsum);
  k_gemm <<<dim3(128, 9, 1), 128, 0, stream>>>(spec, Dbf, part, gram);
  k_lca  <<<512, 256, 0, stream>>>(part, gram, rowsum, psf, out);
}

// Round 9
// 284.747 us; speedup vs baseline: 1.1760x; 1.1148x over previous
//
#include <hip/hip_runtime.h>
#include <hip/hip_bf16.h>
#include <math.h>

// A1SparseCoding: STFT(512,160,hann,center=False) -> |.| -> per-sample norm ->
// LCA (50 iters, lam=0.5, tau=10) -> softshrink(u)
// B=8192, SEG=3200, T=17 frames, F=257 freqs, K=17*257=4369 (pad 4384), N=128 bases.
// spec stored [b][t*257+f]; D's columns permuted identically (dot products invariant).
// STFT: two real frames packed as one complex FFT (a+ib), radix-8 DIT, fp32.
// Ledger: R5: 2x 400MiB harness fills ~120us inside timed iter; boundary ~7us.
//   R6 fail: gram from raw D = scalar-gather latency (+68us kernel).
//   R7 fail: gram fused into k_gemm = 16-wave 137-iter serial tail (+50us).
//   Measured-good: stft+dprep fusion (+1.4us on stft, kills kernel+boundary);
//   R4 gram_mm k-split-8 + gram_fin; R4 k_gemm (128,8); k_lca.
// R8: k_stft FFT math rewritten in packed f32x2 (ext_vector_type(2)) ->
//   v_pk_add/mul/fma_f32 on gfx950: butterflies pair (re,im) exactly, twiddle
//   rotors are complex rotations. ~45% fewer VALU instructions in the FFT core;
//   arithmetic values identical to scalar.
// R9: R8 resubmit unchanged (R8 bench was an infra failure - container never ran).

typedef short bf16x8 __attribute__((ext_vector_type(8)));
typedef float f32x4  __attribute__((ext_vector_type(4)));
typedef float f32x2  __attribute__((ext_vector_type(2)));

#define TWO_PI_OVER_512 0.01227184630f
#define TWO_PI_OVER_64  0.09817477042f
#define C8 0.70710678118654752f

__device__ __forceinline__ unsigned short f2bf(float f){
  unsigned int u = __float_as_uint(f);
  u += 0x7FFFu + ((u >> 16) & 1u);      // RNE; inputs finite
  return (unsigned short)(u >> 16);
}
__device__ __forceinline__ float sshrink(float u){
  float a = fabsf(u) - 0.5f;
  return a > 0.0f ? copysignf(a, u) : 0.0f;
}

// ---------------- radix-8 butterfly (DIT), packed f32x2 ----------------------
// z = {re, im}; (-i)*z = {z.y, -z.x}. Same arithmetic as the scalar form,
// expressed so each op is one v_pk_*_f32 across (re,im).
__device__ __forceinline__ void dft8p(f32x2 z[8]){
  f32x2 t0 = z[0] + z[4], t1 = z[0] - z[4];
  f32x2 t2 = z[2] + z[6], t3 = z[2] - z[6];
  f32x2 e0 = t0 + t2,     e2 = t0 - t2;
  f32x2 mt3 = (f32x2){t3.y, -t3.x};           // (-i)*t3
  f32x2 e1 = t1 + mt3,    e3 = t1 - mt3;
  f32x2 s0 = z[1] + z[5], s1 = z[1] - z[5];
  f32x2 s2 = z[3] + z[7], s3 = z[3] - z[7];
  f32x2 o0 = s0 + s2,     o2 = s0 - s2;
  f32x2 ms3 = (f32x2){s3.y, -s3.x};           // (-i)*s3
  f32x2 o1 = s1 + ms3,    o3 = s1 - ms3;
  z[0] = e0 + o0; z[4] = e0 - o0;
  f32x2 w1 = C8 * (o1 + (f32x2){o1.y, -o1.x});   // {C(o1r+o1i), C(o1i-o1r)}
  z[1] = e1 + w1; z[5] = e1 - w1;
  f32x2 io2 = (f32x2){o2.y, -o2.x};
  z[2] = e2 + io2; z[6] = e2 - io2;
  f32x2 w3 = C8 * ((f32x2){o3.y, -o3.x} - o3);   // {C(o3i-o3r), -C(o3r+o3i)}
  z[3] = e3 + w3; z[7] = e3 - w3;
}

// ---------------- K1: STFT magnitude + moments ‖ D-prep (fused) --------------
// blocks 0..17407: STFT. 4 waves/WG, wave = one FRAME PAIR packed a+ib;
//   private LDS Z slice; zero barriers; rotor twiddles in packed f32x2;
//   epilogue: per-frame s1/s2 on fp32 magnitudes, shfl-reduced, float4/pair.
// blocks 17408..17535: D prep row n = blk-17408 (coalesced fp32 reads, LDS
//   permute k'=t*257+f <- f*17+t, bf16 pack, rowsum). LDS union with Z.
__global__ __launch_bounds__(256) void k_stft(const float* __restrict__ audio,
    const float* __restrict__ D, unsigned short* __restrict__ spec,
    float* __restrict__ psf, unsigned short* __restrict__ Dbf,
    float* __restrict__ rowsum){
  __shared__ __align__(16) char smraw[19712];   // max(4*616*8, 4369*4+256*4)
  const int tid = threadIdx.x;
  const int blk = blockIdx.x;
  if (blk >= 17408){
    // ---- D-prep branch ----
    float* row = (float*)smraw;                 // [4369]
    float* rs  = (float*)(smraw + 17476);       // [256]
    const int n = blk - 17408;
    float acc = 0.0f;
    for (int k = tid; k < 4369; k += 256){
      float v = D[(size_t)n*4369 + k];          // coalesced
      row[k] = v;
      acc += v;
    }
    rs[tid] = acc;
    __syncthreads();
    #pragma unroll
    for (int s = 128; s > 0; s >>= 1){
      if (tid < s) rs[tid] += rs[tid + s];
      __syncthreads();
    }
    if (tid == 0) rowsum[n] = rs[0];
    for (int i = tid; i < 1096; i += 256){
      int k0 = i*4;
      ushort4 pk;
      unsigned short v[4];
      #pragma unroll
      for (int u = 0; u < 4; u++){
        int kp = k0 + u;
        unsigned short r = 0;
        if (kp < 4369){
          int t = kp / 257, f = kp - t*257;
          r = f2bf(row[f*17 + t]);
        }
        v[u] = r;
      }
      pk.x = v[0]; pk.y = v[1]; pk.z = v[2]; pk.w = v[3];
      *(ushort4*)(Dbf + (size_t)n*4384 + k0) = pk;
    }
    return;
  }
  // ---- STFT branch ----
  f32x2 (*zb)[616] = (f32x2(*)[616])smraw;
  const int wid = tid >> 6;
  const int L = tid & 63;
  f32x2* Z = zb[wid];
  const int pair = blk*4 + wid;               // 0..69631
  const int fr0 = pair*2;
  const int b0 = fr0/17, t0 = fr0 - b0*17;
  const int fr1 = fr0 + 1;
  const int b1 = fr1/17, t1 = fr1 - b1*17;
  const float* sA = audio + (size_t)b0*3200 + t0*160;
  const float* sB = audio + (size_t)b1*3200 + t1*160;
  f32x2 z[8];
  // fused digit-reversed load + window; idx=8L+e -> r9 = baseRev+64e.
  // window w(r9) = 0.5 - 0.5 cos(th0 + e*pi/4): packed rotor, 2 transcendentals.
  {
    const int baseRev = ((L & 7) << 3) | (L >> 3);
    float th0 = (float)baseRev * TWO_PI_OVER_512;
    f32x2 w = (f32x2){__cosf(th0), __sinf(th0)};
    #pragma unroll
    for (int e = 0; e < 8; e++){
      int r9 = baseRev + (e << 6);
      float wind = 0.5f - 0.5f*w.x;
      z[e] = (f32x2){sA[r9]*wind, sB[r9]*wind};
      w = C8 * (w + (f32x2){-w.y, w.x});    // rotate by pi/4
    }
  }
  dft8p(z);
  {
    int s0 = 9*L + 5*(L >> 3);                // slot(8L), e contiguous
    #pragma unroll
    for (int e = 0; e < 8; e++) Z[s0 + e] = z[e];
  }
  // stage 1: i = g*64 + j + 8e -> slot = 77g + j + 9e ; W_64^{je} packed rotor
  {
    int j = L & 7, g = L >> 3;
    int sb = 77*g + j;
    #pragma unroll
    for (int e = 0; e < 8; e++) z[e] = Z[sb + 9*e];
    float ang = (float)j * TWO_PI_OVER_64;
    f32x2 w1 = (f32x2){__cosf(ang), __sinf(ang)};   // W = c - i s
    f32x2 w = w1;
    #pragma unroll
    for (int e = 1; e < 8; e++){
      z[e] = z[e]*w.x + (f32x2){z[e].y, -z[e].x}*w.y;   // {ac+bs, bc-as}
      w = w*w1.x + (f32x2){-w.y, w.x}*w1.y;             // rotor advance
    }
    dft8p(z);
    #pragma unroll
    for (int e = 0; e < 8; e++) Z[sb + 9*e] = z[e];
  }
  // stage 2: i = L + 64e -> slot = L + (L>>3) + 77e ; lane L ends with Z[k=L+64f]
  {
    int sb = L + (L >> 3);
    #pragma unroll
    for (int e = 0; e < 8; e++) z[e] = Z[sb + 77*e];
    float ang = (float)L * TWO_PI_OVER_512;
    f32x2 w1 = (f32x2){__cosf(ang), __sinf(ang)};
    f32x2 w = w1;
    #pragma unroll
    for (int e = 1; e < 8; e++){
      z[e] = z[e]*w.x + (f32x2){z[e].y, -z[e].x}*w.y;
      w = w*w1.x + (f32x2){-w.y, w.x}*w1.y;
    }
    dft8p(z);
  }
  // conj-partner exchange: partner of k=L+64f is lane (64-L)&63, reg 7-f (L>=1)
  f32x2 p[4];
  {
    const int partner = (64 - L) & 63;
    #pragma unroll
    for (int f = 0; f < 4; f++){
      p[f].x = __shfl(z[7-f].x, partner);
      p[f].y = __shfl(z[7-f].y, partner);
    }
    if (L == 0){                              // lane 0: partner regs are own (8-f)&7
      p[0] = z[0]; p[1] = z[7]; p[2] = z[6]; p[3] = z[5];
    }
  }
  unsigned short* dA = spec + (size_t)b0*4384 + t0*257;
  unsigned short* dB = spec + (size_t)b1*4384 + t1*257;
  f32x2 s1v = (f32x2){0.f, 0.f}, s2v = (f32x2){0.f, 0.f};
  #pragma unroll
  for (int f = 0; f < 4; f++){
    int k = L + 64*f;
    f32x2 A  = z[f] + (f32x2){p[f].x, -p[f].y};          // {zr+pr, zi-pi}
    f32x2 Bv = (f32x2){z[f].y, -z[f].x} + (f32x2){p[f].y, p[f].x}; // {zi+pi, pr-zr}
    float mA = 0.5f*sqrtf(A.x*A.x + A.y*A.y);
    float mB = 0.5f*sqrtf(Bv.x*Bv.x + Bv.y*Bv.y);
    dA[k] = f2bf(mA);
    dB[k] = f2bf(mB);
    f32x2 m = (f32x2){mA, mB};
    s1v += m;
    s2v += m*m;
  }
  if (L == 0){                                // k=256: Xa=Re(Z[256]), Xb=Im(Z[256])
    float mA = fabsf(z[4].x), mB = fabsf(z[4].y);
    dA[256] = f2bf(mA);
    dB[256] = f2bf(mB);
    s1v += (f32x2){mA, mB};
    s2v += (f32x2){mA*mA, mB*mB};
  }
  float s1A = s1v.x, s2A = s2v.x, s1B = s1v.y, s2B = s2v.y;
  #pragma unroll
  for (int off = 32; off > 0; off >>= 1){
    s1A += __shfl_xor(s1A, off);
    s2A += __shfl_xor(s2A, off);
    s1B += __shfl_xor(s1B, off);
    s2B += __shfl_xor(s2B, off);
  }
  if (L == 0)
    *(float4*)(psf + (size_t)fr0*2) = make_float4(s1A, s2A, s1B, s2B);
  if (t0 == 0 && L < 15) spec[(size_t)b0*4384 + 4369 + L] = 0;
  if (t1 == 0 && L < 15) spec[(size_t)b1*4384 + 4369 + L] = 0;
}

// ---------------- P2: gram = Dbf·Dbfᵀ partials via MFMA (k-split 8) ----------
__global__ __launch_bounds__(64) void k_gram_mm(const unsigned short* __restrict__ Dbf,
    float* __restrict__ pgram){
  const int x = blockIdx.x;                   // 16-row strip, 0..7
  const int ks = blockIdx.y;                  // 0..7
  const int lane = threadIdx.x;
  const int c = lane & 15, q = lane >> 4;
  const unsigned short* ap = Dbf + (size_t)(x*16 + c)*4384 + q*8;
  const unsigned short* bp = Dbf + (size_t)c*4384 + q*8;
  const int t0 = ks*17, t1 = (ks == 7) ? 137 : t0 + 17;
  f32x4 acc[8];
  #pragma unroll
  for (int nt = 0; nt < 8; nt++) acc[nt] = (f32x4){0.f,0.f,0.f,0.f};
  for (int tt = t0; tt < t1; tt++){
    const int k0 = tt*32;
    bf16x8 af = *(const bf16x8*)(ap + k0);
    #pragma unroll
    for (int nt = 0; nt < 8; nt++){
      bf16x8 bfr = *(const bf16x8*)(bp + (size_t)nt*16*4384 + k0);
      acc[nt] = __builtin_amdgcn_mfma_f32_16x16x32_bf16(af, bfr, acc[nt], 0, 0, 0);
    }
  }
  // C layout: row = q*4+r (gram row within strip), col = c (gram col within nt)
  #pragma unroll
  for (int nt = 0; nt < 8; nt++)
    #pragma unroll
    for (int r = 0; r < 4; r++)
      pgram[(size_t)(ks*128 + x*16 + q*4 + r)*128 + nt*16 + c] = acc[nt][r];
}
// deterministic fixed-order sum -> exactly symmetric (MFMA k-order identical for (x,y)/(y,x))
__global__ __launch_bounds__(128) void k_gram_fin(const float* __restrict__ pgram,
    unsigned short* __restrict__ gram_bf){
  const int x = blockIdx.x, y = threadIdx.x;
  float g = ((pgram[(size_t)x*128+y]        + pgram[(size_t)(128+x)*128+y])
          +  (pgram[(size_t)(256+x)*128+y]  + pgram[(size_t)(384+x)*128+y]))
          + ((pgram[(size_t)(512+x)*128+y]  + pgram[(size_t)(640+x)*128+y])
          +  (pgram[(size_t)(768+x)*128+y]  + pgram[(size_t)(896+x)*128+y]));
  if (x == y) g -= 1.0f;
  gram_bf[x*136 + y] = f2bf(g);
}

// ---------------- K4: partial GEMM spec·Dᵀ, M=32/wave, K-split 8 -------------
// grid (128, 8), 128 thr (2 waves). Wave handles rows [mbase, mbase+32):
// 2 A-frags x 8 B-frags = 16 MFMAs per 10 loads per k-step.
__global__ __launch_bounds__(128) void k_gemm(const unsigned short* __restrict__ spec,
    const unsigned short* __restrict__ Dbf, float* __restrict__ part){
  const int mtile = blockIdx.x;               // 0..127 (64 rows per WG)
  const int ks = blockIdx.y;                  // 0..7
  const int wv = threadIdx.x >> 6;
  const int lane = threadIdx.x & 63;
  const int c = lane & 15, q = lane >> 4;
  const int mbase = mtile*64 + wv*32;
  const unsigned short* ap0 = spec + (size_t)(mbase + c)*4384 + q*8;
  const unsigned short* ap1 = ap0 + (size_t)16*4384;
  const unsigned short* bp  = Dbf + (size_t)c*4384 + q*8;
  const int t0 = ks*17, t1 = (ks == 7) ? 137 : t0 + 17;
  f32x4 acc[2][8];
  #pragma unroll
  for (int ar = 0; ar < 2; ar++)
    #pragma unroll
    for (int nt = 0; nt < 8; nt++) acc[ar][nt] = (f32x4){0.f,0.f,0.f,0.f};
  int k0 = t0*32;
  bf16x8 aC0 = *(const bf16x8*)(ap0 + k0);
  bf16x8 aC1 = *(const bf16x8*)(ap1 + k0);
  bf16x8 bC[8];
  #pragma unroll
  for (int nt = 0; nt < 8; nt++)
    bC[nt] = *(const bf16x8*)(bp + (size_t)nt*16*4384 + k0);
  for (int tt = t0; tt < t1; tt++){
    const int tn = (tt + 1 < t1) ? tt + 1 : tt;
    const int kn = tn*32;
    bf16x8 aN0 = *(const bf16x8*)(ap0 + kn);
    bf16x8 aN1 = *(const bf16x8*)(ap1 + kn);
    bf16x8 bN[8];
    #pragma unroll
    for (int nt = 0; nt < 8; nt++)
      bN[nt] = *(const bf16x8*)(bp + (size_t)nt*16*4384 + kn);
    #pragma unroll
    for (int nt = 0; nt < 8; nt++){
      acc[0][nt] = __builtin_amdgcn_mfma_f32_16x16x32_bf16(aC0, bC[nt], acc[0][nt], 0, 0, 0);
      acc[1][nt] = __builtin_amdgcn_mfma_f32_16x16x32_bf16(aC1, bC[nt], acc[1][nt], 0, 0, 0);
    }
    aC0 = aN0; aC1 = aN1;
    #pragma unroll
    for (int nt = 0; nt < 8; nt++) bC[nt] = bN[nt];
  }
  // part[ks][n][m]: n = nt*16+c, m = mbase + ar*16 + q*4 + r
  #pragma unroll
  for (int nt = 0; nt < 8; nt++){
    float* b0 = part + ((size_t)(ks*128 + nt*16 + c))*8192 + mbase + q*4;
    *(f32x4*)(b0)      = acc[0][nt];
    *(f32x4*)(b0 + 16) = acc[1][nt];
  }
}

// ---------------- K5: LCA, 50 iters. rᵀ = G·aᵀ; 4 waves x 32 gram rows ------
// 512 blocks x 256 thr: block = 16 samples; wave wv owns rows [wv*32, wv*32+32).
// a exchanged via double-buffered LDS, ONE barrier per iter.
__global__ __launch_bounds__(256) void k_lca(const float* __restrict__ part,
    const unsigned short* __restrict__ gram_bf, const float* __restrict__ rowsum,
    const float* __restrict__ psf, float* __restrict__ out){
  __shared__ unsigned short A[2][16*136];
  const int tid = threadIdx.x, wv = tid >> 6, lane = tid & 63;
  const int c = lane & 15, q = lane >> 4;
  const int sg = blockIdx.x*16 + c;
  // moments: sum 17 per-frame (s1,s2) pairs (fp32, fixed order)
  const float* pf = psf + (size_t)sg*34;
  float S1 = 0.f, S2 = 0.f;
  #pragma unroll
  for (int t = 0; t < 17; t++){
    S1 += pf[2*t];
    S2 += pf[2*t + 1];
  }
  const float mus = S1 / 4369.0f;
  float var = (S2 - S1*S1/4369.0f) / 4368.0f;
  var = fmaxf(var, 0.0f);
  const float invs = 1.0f / (sqrtf(var) + 1e-8f);
  const int nb = wv*32;
  bf16x8 Gf[2][4];                            // A-frags of G rows [nb, nb+32)
  #pragma unroll
  for (int rt = 0; rt < 2; rt++)
    #pragma unroll
    for (int kt = 0; kt < 4; kt++)
      Gf[rt][kt] = *(const bf16x8*)(gram_bf + (size_t)(nb + rt*16 + c)*136 + kt*32 + q*8);
  f32x4 U[2], Bb[2];
  #pragma unroll
  for (int rt = 0; rt < 2; rt++){
    #pragma unroll
    for (int r = 0; r < 4; r++){
      int n = nb + rt*16 + q*4 + r;
      float S = 0.f;
      #pragma unroll
      for (int s = 0; s < 8; s++)
        S += part[((size_t)(s*128 + n))*8192 + sg];
      Bb[rt][r] = invs * (S - mus * rowsum[n]);
      U[rt][r] = 0.0f;
    }
  }
  for (int it = 0; it < 50; it++){
    unsigned short* Ab = A[it & 1];
    #pragma unroll
    for (int rt = 0; rt < 2; rt++){
      ushort4 pk;
      pk.x = f2bf(sshrink(U[rt][0]));
      pk.y = f2bf(sshrink(U[rt][1]));
      pk.z = f2bf(sshrink(U[rt][2]));
      pk.w = f2bf(sshrink(U[rt][3]));
      *(ushort4*)(Ab + c*136 + nb + rt*16 + q*4) = pk;
    }
    __syncthreads();
    bf16x8 af[4];
    #pragma unroll
    for (int kt = 0; kt < 4; kt++)            // B-frag: aᵀ[k][sample=c]
      af[kt] = *(const bf16x8*)(Ab + c*136 + kt*32 + q*8);
    f32x4 R[2];
    R[0] = (f32x4){0.f,0.f,0.f,0.f};
    R[1] = (f32x4){0.f,0.f,0.f,0.f};
    #pragma unroll
    for (int kt = 0; kt < 4; kt++)            // kt outer: R[0],R[1] chains interleave
      #pragma unroll
      for (int rt = 0; rt < 2; rt++)
        R[rt] = __builtin_amdgcn_mfma_f32_16x16x32_bf16(Gf[rt][kt], af[kt], R[rt], 0, 0, 0);
    #pragma unroll
    for (int rt = 0; rt < 2; rt++){
      #pragma unroll
      for (int r = 0; r < 4; r++){
        float u = U[rt][r];
        U[rt][r] = u + (Bb[rt][r] - u - R[rt][r]) * 0.1f;
      }
    }
  }
  #pragma unroll
  for (int rt = 0; rt < 2; rt++){
    float4 o;
    o.x = sshrink(U[rt][0]);
    o.y = sshrink(U[rt][1]);
    o.z = sshrink(U[rt][2]);
    o.w = sshrink(U[rt][3]);
    *(float4*)(out + (size_t)sg*128 + nb + rt*16 + q*4) = o;
  }
}

// ---------------- launch ----------------
extern "C" void kernel_launch(void* const* d_in, const int* in_sizes, int n_in,
                              void* d_out, int out_size, void* d_ws, size_t ws_size,
                              hipStream_t stream){
  const float* audio = (const float*)d_in[0];   // 8192*3200
  const float* D     = (const float*)d_in[1];   // 128*4369
  float* out = (float*)d_out;                   // 8192*128 f32
  char* ws = (char*)d_ws;
  // workspace layout, total ~108.2 MB
  unsigned short* spec   = (unsigned short*)(ws);               // 71,827,456
  float*          part   = (float*)(ws + 71827456);             // 33,554,432 (8 slices)
  unsigned short* Dbf    = (unsigned short*)(ws + 105381888);   // 1,122,304
  unsigned short* gram   = (unsigned short*)(ws + 106504192);   // 34,816
  float*          pgram  = (float*)(ws + 106539008);            // 524,288
  float*          rowsum = (float*)(ws + 107063296);            // 512
  float*          psf    = (float*)(ws + 107063808);            // 1,114,112 (8192*17*2)

  k_stft    <<<17536, 256, 0, stream>>>(audio, D, spec, psf, Dbf, rowsum);
  k_gram_mm <<<dim3(8, 8, 1), 64, 0, stream>>>(Dbf, pgram);
  k_gram_fin<<<128, 128, 0, stream>>>(pgram, gram);
  k_gemm    <<<dim3(128, 8, 1), 128, 0, stream>>>(spec, Dbf, part);
  k_lca     <<<512, 256, 0, stream>>>(part, gram, rowsum, psf, out);
}

// Round 10
// 276.429 us; speedup vs baseline: 1.2114x; 1.0301x over previous
//
#include <hip/hip_runtime.h>
#include <hip/hip_bf16.h>
#include <math.h>

// A1SparseCoding: STFT(512,160,hann,center=False) -> |.| -> per-sample norm ->
// LCA (50 iters, lam=0.5, tau=10) -> softshrink(u)
// B=8192, SEG=3200, T=17 frames, F=257 freqs, K=17*257=4369 (pad 4384), N=128 bases.
// spec stored [b][t*257+f]; D's columns permuted identically (dot products invariant).
// STFT: two real frames packed as one complex FFT (a+ib), radix-8 DIT, fp32.
// Ledger: R5: 2x 400MiB harness fills ~120us inside timed iter; boundary ~7us.
//   R6 fail: gram from raw D = scalar-gather latency. R7 fail: full-K gram fused
//   into k_gemm = 137-iter serial tail (+50us). R9: packed f32x2 FFT = -4.5us
//   (partial pk lowering; VGPR 32->24, VALUBusy 82->74%).
//   Measured-good: stft+dprep fusion; k-split-8 gram; R4 k_gemm; k_lca.
// R10: (a) k_gram_mm fused into k_gemm grid y==8 (64 blocks x 2 waves x 17
//   iters - matched length, no serial tail; same pgram layout + k-order ->
//   gram bit-identical). 5->4 launches. (b) 0.5 magnitude factor folded into
//   window (R2-verified: wind=0.25-0.25cos, Nyquist *2).

typedef short bf16x8 __attribute__((ext_vector_type(8)));
typedef float f32x4  __attribute__((ext_vector_type(4)));
typedef float f32x2  __attribute__((ext_vector_type(2)));

#define TWO_PI_OVER_512 0.01227184630f
#define TWO_PI_OVER_64  0.09817477042f
#define C8 0.70710678118654752f

__device__ __forceinline__ unsigned short f2bf(float f){
  unsigned int u = __float_as_uint(f);
  u += 0x7FFFu + ((u >> 16) & 1u);      // RNE; inputs finite
  return (unsigned short)(u >> 16);
}
__device__ __forceinline__ float sshrink(float u){
  float a = fabsf(u) - 0.5f;
  return a > 0.0f ? copysignf(a, u) : 0.0f;
}

// ---------------- radix-8 butterfly (DIT), packed f32x2 ----------------------
// z = {re, im}; (-i)*z = {z.y, -z.x}. Same arithmetic as the scalar form,
// expressed so each op can lower to v_pk_*_f32 across (re,im).
__device__ __forceinline__ void dft8p(f32x2 z[8]){
  f32x2 t0 = z[0] + z[4], t1 = z[0] - z[4];
  f32x2 t2 = z[2] + z[6], t3 = z[2] - z[6];
  f32x2 e0 = t0 + t2,     e2 = t0 - t2;
  f32x2 mt3 = (f32x2){t3.y, -t3.x};           // (-i)*t3
  f32x2 e1 = t1 + mt3,    e3 = t1 - mt3;
  f32x2 s0 = z[1] + z[5], s1 = z[1] - z[5];
  f32x2 s2 = z[3] + z[7], s3 = z[3] - z[7];
  f32x2 o0 = s0 + s2,     o2 = s0 - s2;
  f32x2 ms3 = (f32x2){s3.y, -s3.x};           // (-i)*s3
  f32x2 o1 = s1 + ms3,    o3 = s1 - ms3;
  z[0] = e0 + o0; z[4] = e0 - o0;
  f32x2 w1 = C8 * (o1 + (f32x2){o1.y, -o1.x});   // {C(o1r+o1i), C(o1i-o1r)}
  z[1] = e1 + w1; z[5] = e1 - w1;
  f32x2 io2 = (f32x2){o2.y, -o2.x};
  z[2] = e2 + io2; z[6] = e2 - io2;
  f32x2 w3 = C8 * ((f32x2){o3.y, -o3.x} - o3);   // {C(o3i-o3r), -C(o3r+o3i)}
  z[3] = e3 + w3; z[7] = e3 - w3;
}

// ---------------- K1: STFT magnitude + moments ‖ D-prep (fused) --------------
// blocks 0..17407: STFT. 4 waves/WG, wave = one FRAME PAIR packed a+ib;
//   private LDS Z slice; zero barriers; rotor twiddles in packed f32x2;
//   epilogue: per-frame s1/s2 on fp32 magnitudes, shfl-reduced, float4/pair.
//   Window carries the 0.5 magnitude factor (0.25-0.25cos); Nyquist gets *2.
// blocks 17408..17535: D prep row n = blk-17408 (coalesced fp32 reads, LDS
//   permute k'=t*257+f <- f*17+t, bf16 pack, rowsum). LDS union with Z.
__global__ __launch_bounds__(256) void k_stft(const float* __restrict__ audio,
    const float* __restrict__ D, unsigned short* __restrict__ spec,
    float* __restrict__ psf, unsigned short* __restrict__ Dbf,
    float* __restrict__ rowsum){
  __shared__ __align__(16) char smraw[19712];   // max(4*616*8, 4369*4+256*4)
  const int tid = threadIdx.x;
  const int blk = blockIdx.x;
  if (blk >= 17408){
    // ---- D-prep branch ----
    float* row = (float*)smraw;                 // [4369]
    float* rs  = (float*)(smraw + 17476);       // [256]
    const int n = blk - 17408;
    float acc = 0.0f;
    for (int k = tid; k < 4369; k += 256){
      float v = D[(size_t)n*4369 + k];          // coalesced
      row[k] = v;
      acc += v;
    }
    rs[tid] = acc;
    __syncthreads();
    #pragma unroll
    for (int s = 128; s > 0; s >>= 1){
      if (tid < s) rs[tid] += rs[tid + s];
      __syncthreads();
    }
    if (tid == 0) rowsum[n] = rs[0];
    for (int i = tid; i < 1096; i += 256){
      int k0 = i*4;
      ushort4 pk;
      unsigned short v[4];
      #pragma unroll
      for (int u = 0; u < 4; u++){
        int kp = k0 + u;
        unsigned short r = 0;
        if (kp < 4369){
          int t = kp / 257, f = kp - t*257;
          r = f2bf(row[f*17 + t]);
        }
        v[u] = r;
      }
      pk.x = v[0]; pk.y = v[1]; pk.z = v[2]; pk.w = v[3];
      *(ushort4*)(Dbf + (size_t)n*4384 + k0) = pk;
    }
    return;
  }
  // ---- STFT branch ----
  f32x2 (*zb)[616] = (f32x2(*)[616])smraw;
  const int wid = tid >> 6;
  const int L = tid & 63;
  f32x2* Z = zb[wid];
  const int pair = blk*4 + wid;               // 0..69631
  const int fr0 = pair*2;
  const int b0 = fr0/17, t0 = fr0 - b0*17;
  const int fr1 = fr0 + 1;
  const int b1 = fr1/17, t1 = fr1 - b1*17;
  const float* sA = audio + (size_t)b0*3200 + t0*160;
  const float* sB = audio + (size_t)b1*3200 + t1*160;
  f32x2 z[8];
  // fused digit-reversed load + window; idx=8L+e -> r9 = baseRev+64e.
  // window w(r9) = 0.25 - 0.25 cos(th0 + e*pi/4): hann * 0.5 mag factor.
  {
    const int baseRev = ((L & 7) << 3) | (L >> 3);
    float th0 = (float)baseRev * TWO_PI_OVER_512;
    f32x2 w = (f32x2){__cosf(th0), __sinf(th0)};
    #pragma unroll
    for (int e = 0; e < 8; e++){
      int r9 = baseRev + (e << 6);
      float wind = 0.25f - 0.25f*w.x;
      z[e] = (f32x2){sA[r9]*wind, sB[r9]*wind};
      w = C8 * (w + (f32x2){-w.y, w.x});    // rotate by pi/4
    }
  }
  dft8p(z);
  {
    int s0 = 9*L + 5*(L >> 3);                // slot(8L), e contiguous
    #pragma unroll
    for (int e = 0; e < 8; e++) Z[s0 + e] = z[e];
  }
  // stage 1: i = g*64 + j + 8e -> slot = 77g + j + 9e ; W_64^{je} packed rotor
  {
    int j = L & 7, g = L >> 3;
    int sb = 77*g + j;
    #pragma unroll
    for (int e = 0; e < 8; e++) z[e] = Z[sb + 9*e];
    float ang = (float)j * TWO_PI_OVER_64;
    f32x2 w1 = (f32x2){__cosf(ang), __sinf(ang)};   // W = c - i s
    f32x2 w = w1;
    #pragma unroll
    for (int e = 1; e < 8; e++){
      z[e] = z[e]*w.x + (f32x2){z[e].y, -z[e].x}*w.y;   // {ac+bs, bc-as}
      w = w*w1.x + (f32x2){-w.y, w.x}*w1.y;             // rotor advance
    }
    dft8p(z);
    #pragma unroll
    for (int e = 0; e < 8; e++) Z[sb + 9*e] = z[e];
  }
  // stage 2: i = L + 64e -> slot = L + (L>>3) + 77e ; lane L ends with Z[k=L+64f]
  {
    int sb = L + (L >> 3);
    #pragma unroll
    for (int e = 0; e < 8; e++) z[e] = Z[sb + 77*e];
    float ang = (float)L * TWO_PI_OVER_512;
    f32x2 w1 = (f32x2){__cosf(ang), __sinf(ang)};
    f32x2 w = w1;
    #pragma unroll
    for (int e = 1; e < 8; e++){
      z[e] = z[e]*w.x + (f32x2){z[e].y, -z[e].x}*w.y;
      w = w*w1.x + (f32x2){-w.y, w.x}*w1.y;
    }
    dft8p(z);
  }
  // conj-partner exchange: partner of k=L+64f is lane (64-L)&63, reg 7-f (L>=1)
  f32x2 p[4];
  {
    const int partner = (64 - L) & 63;
    #pragma unroll
    for (int f = 0; f < 4; f++){
      p[f].x = __shfl(z[7-f].x, partner);
      p[f].y = __shfl(z[7-f].y, partner);
    }
    if (L == 0){                              // lane 0: partner regs are own (8-f)&7
      p[0] = z[0]; p[1] = z[7]; p[2] = z[6]; p[3] = z[5];
    }
  }
  unsigned short* dA = spec + (size_t)b0*4384 + t0*257;
  unsigned short* dB = spec + (size_t)b1*4384 + t1*257;
  f32x2 s1v = (f32x2){0.f, 0.f}, s2v = (f32x2){0.f, 0.f};
  #pragma unroll
  for (int f = 0; f < 4; f++){
    int k = L + 64*f;
    f32x2 A  = z[f] + (f32x2){p[f].x, -p[f].y};          // {zr+pr, zi-pi}
    f32x2 Bv = (f32x2){z[f].y, -z[f].x} + (f32x2){p[f].y, p[f].x}; // {zi+pi, pr-zr}
    float mA = sqrtf(A.x*A.x + A.y*A.y);      // 0.5 folded into window
    float mB = sqrtf(Bv.x*Bv.x + Bv.y*Bv.y);
    dA[k] = f2bf(mA);
    dB[k] = f2bf(mB);
    f32x2 m = (f32x2){mA, mB};
    s1v += m;
    s2v += m*m;
  }
  if (L == 0){                                // k=256: Z pre-halved -> *2 (no
    float mA = 2.0f*fabsf(z[4].x);            // conj-combine 0.5 at Nyquist)
    float mB = 2.0f*fabsf(z[4].y);
    dA[256] = f2bf(mA);
    dB[256] = f2bf(mB);
    s1v += (f32x2){mA, mB};
    s2v += (f32x2){mA*mA, mB*mB};
  }
  float s1A = s1v.x, s2A = s2v.x, s1B = s1v.y, s2B = s2v.y;
  #pragma unroll
  for (int off = 32; off > 0; off >>= 1){
    s1A += __shfl_xor(s1A, off);
    s2A += __shfl_xor(s2A, off);
    s1B += __shfl_xor(s1B, off);
    s2B += __shfl_xor(s2B, off);
  }
  if (L == 0)
    *(float4*)(psf + (size_t)fr0*2) = make_float4(s1A, s2A, s1B, s2B);
  if (t0 == 0 && L < 15) spec[(size_t)b0*4384 + 4369 + L] = 0;
  if (t1 == 0 && L < 15) spec[(size_t)b1*4384 + 4369 + L] = 0;
}

// ---------------- K4: partial GEMM spec·Dᵀ ‖ gram partials (fused) -----------
// grid (128, 9), 128 thr (2 waves).
// y<8: GEMM k-slice, wave = rows [mbase, mbase+32): 16 MFMA : 10 loads / step.
// y==8, x<64: gram partial strip x>>3, ks x&7 (17 iters - matched length, no
//   serial tail). Wave w computes nt w*4..w*4+3. Same pgram layout + ascending
//   k-order as the old k_gram_mm -> gram_fin result bit-identical.
__global__ __launch_bounds__(128) void k_gemm(const unsigned short* __restrict__ spec,
    const unsigned short* __restrict__ Dbf, float* __restrict__ part,
    float* __restrict__ pgram){
  const int lane = threadIdx.x & 63;
  const int c = lane & 15, q = lane >> 4;
  const int wv = threadIdx.x >> 6;
  if (blockIdx.y == 8){
    if (blockIdx.x >= 64) return;
    const int x = blockIdx.x >> 3;            // strip 0..7
    const int ks = blockIdx.x & 7;            // 0..7
    const unsigned short* ap = Dbf + (size_t)(x*16 + c)*4384 + q*8;
    const unsigned short* bp = Dbf + (size_t)c*4384 + q*8;
    const int t0 = ks*17, t1 = (ks == 7) ? 137 : t0 + 17;
    f32x4 acc[4];
    #pragma unroll
    for (int i = 0; i < 4; i++) acc[i] = (f32x4){0.f,0.f,0.f,0.f};
    for (int tt = t0; tt < t1; tt++){
      const int k0 = tt*32;
      bf16x8 af = *(const bf16x8*)(ap + k0);
      #pragma unroll
      for (int i = 0; i < 4; i++){
        const int nt = wv*4 + i;
        bf16x8 bfr = *(const bf16x8*)(bp + (size_t)nt*16*4384 + k0);
        acc[i] = __builtin_amdgcn_mfma_f32_16x16x32_bf16(af, bfr, acc[i], 0, 0, 0);
      }
    }
    #pragma unroll
    for (int i = 0; i < 4; i++){
      const int nt = wv*4 + i;
      #pragma unroll
      for (int r = 0; r < 4; r++)
        pgram[(size_t)(ks*128 + x*16 + q*4 + r)*128 + nt*16 + c] = acc[i][r];
    }
    return;
  }
  const int mtile = blockIdx.x;               // 0..127 (64 rows per WG)
  const int ks = blockIdx.y;                  // 0..7
  const int mbase = mtile*64 + wv*32;
  const unsigned short* ap0 = spec + (size_t)(mbase + c)*4384 + q*8;
  const unsigned short* ap1 = ap0 + (size_t)16*4384;
  const unsigned short* bp  = Dbf + (size_t)c*4384 + q*8;
  const int t0 = ks*17, t1 = (ks == 7) ? 137 : t0 + 17;
  f32x4 acc[2][8];
  #pragma unroll
  for (int ar = 0; ar < 2; ar++)
    #pragma unroll
    for (int nt = 0; nt < 8; nt++) acc[ar][nt] = (f32x4){0.f,0.f,0.f,0.f};
  int k0 = t0*32;
  bf16x8 aC0 = *(const bf16x8*)(ap0 + k0);
  bf16x8 aC1 = *(const bf16x8*)(ap1 + k0);
  bf16x8 bC[8];
  #pragma unroll
  for (int nt = 0; nt < 8; nt++)
    bC[nt] = *(const bf16x8*)(bp + (size_t)nt*16*4384 + k0);
  for (int tt = t0; tt < t1; tt++){
    const int tn = (tt + 1 < t1) ? tt + 1 : tt;
    const int kn = tn*32;
    bf16x8 aN0 = *(const bf16x8*)(ap0 + kn);
    bf16x8 aN1 = *(const bf16x8*)(ap1 + kn);
    bf16x8 bN[8];
    #pragma unroll
    for (int nt = 0; nt < 8; nt++)
      bN[nt] = *(const bf16x8*)(bp + (size_t)nt*16*4384 + kn);
    #pragma unroll
    for (int nt = 0; nt < 8; nt++){
      acc[0][nt] = __builtin_amdgcn_mfma_f32_16x16x32_bf16(aC0, bC[nt], acc[0][nt], 0, 0, 0);
      acc[1][nt] = __builtin_amdgcn_mfma_f32_16x16x32_bf16(aC1, bC[nt], acc[1][nt], 0, 0, 0);
    }
    aC0 = aN0; aC1 = aN1;
    #pragma unroll
    for (int nt = 0; nt < 8; nt++) bC[nt] = bN[nt];
  }
  // part[ks][n][m]: n = nt*16+c, m = mbase + ar*16 + q*4 + r
  #pragma unroll
  for (int nt = 0; nt < 8; nt++){
    float* b0 = part + ((size_t)(ks*128 + nt*16 + c))*8192 + mbase + q*4;
    *(f32x4*)(b0)      = acc[0][nt];
    *(f32x4*)(b0 + 16) = acc[1][nt];
  }
}

// deterministic fixed-order sum -> exactly symmetric (MFMA k-order identical for (x,y)/(y,x))
__global__ __launch_bounds__(128) void k_gram_fin(const float* __restrict__ pgram,
    unsigned short* __restrict__ gram_bf){
  const int x = blockIdx.x, y = threadIdx.x;
  float g = ((pgram[(size_t)x*128+y]        + pgram[(size_t)(128+x)*128+y])
          +  (pgram[(size_t)(256+x)*128+y]  + pgram[(size_t)(384+x)*128+y]))
          + ((pgram[(size_t)(512+x)*128+y]  + pgram[(size_t)(640+x)*128+y])
          +  (pgram[(size_t)(768+x)*128+y]  + pgram[(size_t)(896+x)*128+y]));
  if (x == y) g -= 1.0f;
  gram_bf[x*136 + y] = f2bf(g);
}

// ---------------- K5: LCA, 50 iters. rᵀ = G·aᵀ; 4 waves x 32 gram rows ------
// 512 blocks x 256 thr: block = 16 samples; wave wv owns rows [wv*32, wv*32+32).
// a exchanged via double-buffered LDS, ONE barrier per iter.
__global__ __launch_bounds__(256) void k_lca(const float* __restrict__ part,
    const unsigned short* __restrict__ gram_bf, const float* __restrict__ rowsum,
    const float* __restrict__ psf, float* __restrict__ out){
  __shared__ unsigned short A[2][16*136];
  const int tid = threadIdx.x, wv = tid >> 6, lane = tid & 63;
  const int c = lane & 15, q = lane >> 4;
  const int sg = blockIdx.x*16 + c;
  // moments: sum 17 per-frame (s1,s2) pairs (fp32, fixed order)
  const float* pf = psf + (size_t)sg*34;
  float S1 = 0.f, S2 = 0.f;
  #pragma unroll
  for (int t = 0; t < 17; t++){
    S1 += pf[2*t];
    S2 += pf[2*t + 1];
  }
  const float mus = S1 / 4369.0f;
  float var = (S2 - S1*S1/4369.0f) / 4368.0f;
  var = fmaxf(var, 0.0f);
  const float invs = 1.0f / (sqrtf(var) + 1e-8f);
  const int nb = wv*32;
  bf16x8 Gf[2][4];                            // A-frags of G rows [nb, nb+32)
  #pragma unroll
  for (int rt = 0; rt < 2; rt++)
    #pragma unroll
    for (int kt = 0; kt < 4; kt++)
      Gf[rt][kt] = *(const bf16x8*)(gram_bf + (size_t)(nb + rt*16 + c)*136 + kt*32 + q*8);
  f32x4 U[2], Bb[2];
  #pragma unroll
  for (int rt = 0; rt < 2; rt++){
    #pragma unroll
    for (int r = 0; r < 4; r++){
      int n = nb + rt*16 + q*4 + r;
      float S = 0.f;
      #pragma unroll
      for (int s = 0; s < 8; s++)
        S += part[((size_t)(s*128 + n))*8192 + sg];
      Bb[rt][r] = invs * (S - mus * rowsum[n]);
      U[rt][r] = 0.0f;
    }
  }
  for (int it = 0; it < 50; it++){
    unsigned short* Ab = A[it & 1];
    #pragma unroll
    for (int rt = 0; rt < 2; rt++){
      ushort4 pk;
      pk.x = f2bf(sshrink(U[rt][0]));
      pk.y = f2bf(sshrink(U[rt][1]));
      pk.z = f2bf(sshrink(U[rt][2]));
      pk.w = f2bf(sshrink(U[rt][3]));
      *(ushort4*)(Ab + c*136 + nb + rt*16 + q*4) = pk;
    }
    __syncthreads();
    bf16x8 af[4];
    #pragma unroll
    for (int kt = 0; kt < 4; kt++)            // B-frag: aᵀ[k][sample=c]
      af[kt] = *(const bf16x8*)(Ab + c*136 + kt*32 + q*8);
    f32x4 R[2];
    R[0] = (f32x4){0.f,0.f,0.f,0.f};
    R[1] = (f32x4){0.f,0.f,0.f,0.f};
    #pragma unroll
    for (int kt = 0; kt < 4; kt++)            // kt outer: R[0],R[1] chains interleave
      #pragma unroll
      for (int rt = 0; rt < 2; rt++)
        R[rt] = __builtin_amdgcn_mfma_f32_16x16x32_bf16(Gf[rt][kt], af[kt], R[rt], 0, 0, 0);
    #pragma unroll
    for (int rt = 0; rt < 2; rt++){
      #pragma unroll
      for (int r = 0; r < 4; r++){
        float u = U[rt][r];
        U[rt][r] = u + (Bb[rt][r] - u - R[rt][r]) * 0.1f;
      }
    }
  }
  #pragma unroll
  for (int rt = 0; rt < 2; rt++){
    float4 o;
    o.x = sshrink(U[rt][0]);
    o.y = sshrink(U[rt][1]);
    o.z = sshrink(U[rt][2]);
    o.w = sshrink(U[rt][3]);
    *(float4*)(out + (size_t)sg*128 + nb + rt*16 + q*4) = o;
  }
}

// ---------------- launch ----------------
extern "C" void kernel_launch(void* const* d_in, const int* in_sizes, int n_in,
                              void* d_out, int out_size, void* d_ws, size_t ws_size,
                              hipStream_t stream){
  const float* audio = (const float*)d_in[0];   // 8192*3200
  const float* D     = (const float*)d_in[1];   // 128*4369
  float* out = (float*)d_out;                   // 8192*128 f32
  char* ws = (char*)d_ws;
  // workspace layout, total ~108.2 MB
  unsigned short* spec   = (unsigned short*)(ws);               // 71,827,456
  float*          part   = (float*)(ws + 71827456);             // 33,554,432 (8 slices)
  unsigned short* Dbf    = (unsigned short*)(ws + 105381888);   // 1,122,304
  unsigned short* gram   = (unsigned short*)(ws + 106504192);   // 34,816
  float*          pgram  = (float*)(ws + 106539008);            // 524,288
  float*          rowsum = (float*)(ws + 107063296);            // 512
  float*          psf    = (float*)(ws + 107063808);            // 1,114,112 (8192*17*2)

  k_stft    <<<17536, 256, 0, stream>>>(audio, D, spec, psf, Dbf, rowsum);
  k_gemm    <<<dim3(128, 9, 1), 128, 0, stream>>>(spec, Dbf, part, pgram);
  k_gram_fin<<<128, 128, 0, stream>>>(pgram, gram);
  k_lca     <<<512, 256, 0, stream>>>(part, gram, rowsum, psf, out);
}

// Round 11
// 274.788 us; speedup vs baseline: 1.2186x; 1.0060x over previous
//
#include <hip/hip_runtime.h>
#include <hip/hip_bf16.h>
#include <math.h>

// A1SparseCoding: STFT(512,160,hann,center=False) -> |.| -> per-sample norm ->
// LCA (50 iters, lam=0.5, tau=10) -> softshrink(u)
// B=8192, SEG=3200, T=17 frames, F=257 freqs, K=17*257=4369 (pad 4384), N=128 bases.
// spec stored [b][t*257+f]; D's columns permuted identically (dot products invariant).
// STFT: two real frames packed as one complex FFT (a+ib), radix-8 DIT, fp32.
// Ledger: R5: 2x 400MiB harness fills ~120us inside timed iter; boundary ~7us.
//   R6 fail: gram from raw D = scalar gather. R7 fail: full-K gram tail in gemm.
//   R9: packed f32x2 FFT -4.5us. R10: gram partials fused in gemm y==8 (matched
//   17-iter length) + window 0.5-fold = 276.4us best.
// R11: twiddle/window generators depth-7 recurrences -> depth-<=3 trees.
//   Window: r=e^{i pi/4}, r^2=i -> all 8 wind_e from {c0,s0,c1,s1} (+-affine).
//   Stages: W^e squaring tree (W2=W^2,W4=W2^2,W3=W2*W,W5=W4*W,W6=W3^2,W7=W4*W3).
//   Same op count, half the dependent-chain depth -> targets the ~27% VALU idle.

typedef short bf16x8 __attribute__((ext_vector_type(8)));
typedef float f32x4  __attribute__((ext_vector_type(4)));
typedef float f32x2  __attribute__((ext_vector_type(2)));

#define TWO_PI_OVER_512 0.01227184630f
#define TWO_PI_OVER_64  0.09817477042f
#define C8 0.70710678118654752f

__device__ __forceinline__ unsigned short f2bf(float f){
  unsigned int u = __float_as_uint(f);
  u += 0x7FFFu + ((u >> 16) & 1u);      // RNE; inputs finite
  return (unsigned short)(u >> 16);
}
__device__ __forceinline__ float sshrink(float u){
  float a = fabsf(u) - 0.5f;
  return a > 0.0f ? copysignf(a, u) : 0.0f;
}
__device__ __forceinline__ f32x2 cmul(f32x2 a, f32x2 b){
  return (f32x2){a.x*b.x - a.y*b.y, a.x*b.y + a.y*b.x};
}
__device__ __forceinline__ f32x2 csq(f32x2 a){
  return (f32x2){a.x*a.x - a.y*a.y, 2.0f*a.x*a.y};
}

// ---------------- radix-8 butterfly (DIT), packed f32x2 ----------------------
// z = {re, im}; (-i)*z = {z.y, -z.x}. Same arithmetic as the scalar form,
// expressed so each op can lower to v_pk_*_f32 across (re,im).
__device__ __forceinline__ void dft8p(f32x2 z[8]){
  f32x2 t0 = z[0] + z[4], t1 = z[0] - z[4];
  f32x2 t2 = z[2] + z[6], t3 = z[2] - z[6];
  f32x2 e0 = t0 + t2,     e2 = t0 - t2;
  f32x2 mt3 = (f32x2){t3.y, -t3.x};           // (-i)*t3
  f32x2 e1 = t1 + mt3,    e3 = t1 - mt3;
  f32x2 s0 = z[1] + z[5], s1 = z[1] - z[5];
  f32x2 s2 = z[3] + z[7], s3 = z[3] - z[7];
  f32x2 o0 = s0 + s2,     o2 = s0 - s2;
  f32x2 ms3 = (f32x2){s3.y, -s3.x};           // (-i)*s3
  f32x2 o1 = s1 + ms3,    o3 = s1 - ms3;
  z[0] = e0 + o0; z[4] = e0 - o0;
  f32x2 w1 = C8 * (o1 + (f32x2){o1.y, -o1.x});   // {C(o1r+o1i), C(o1i-o1r)}
  z[1] = e1 + w1; z[5] = e1 - w1;
  f32x2 io2 = (f32x2){o2.y, -o2.x};
  z[2] = e2 + io2; z[6] = e2 - io2;
  f32x2 w3 = C8 * ((f32x2){o3.y, -o3.x} - o3);   // {C(o3i-o3r), -C(o3r+o3i)}
  z[3] = e3 + w3; z[7] = e3 - w3;
}

// apply twiddle W[e]={cos ea, sin ea} (tree-built) to z[1..7]:
// z = {a*c + b*s, b*c - a*s}
__device__ __forceinline__ void twiddle_apply(f32x2 z[8], f32x2 W1){
  f32x2 W2 = csq(W1);
  f32x2 W4 = csq(W2);
  f32x2 W3 = cmul(W2, W1);
  f32x2 W5 = cmul(W4, W1);
  f32x2 W6 = csq(W3);
  f32x2 W7 = cmul(W4, W3);
  f32x2 W[8];
  W[1]=W1; W[2]=W2; W[3]=W3; W[4]=W4; W[5]=W5; W[6]=W6; W[7]=W7;
  #pragma unroll
  for (int e = 1; e < 8; e++){
    f32x2 v = z[e];
    z[e] = (f32x2){v.x*W[e].x + v.y*W[e].y, v.y*W[e].x - v.x*W[e].y};
  }
}

// ---------------- K1: STFT magnitude + moments ‖ D-prep (fused) --------------
// blocks 0..17407: STFT. 4 waves/WG, wave = one FRAME PAIR packed a+ib;
//   private LDS Z slice; zero barriers; tree twiddles in packed f32x2;
//   epilogue: per-frame s1/s2 on fp32 magnitudes, shfl-reduced, float4/pair.
//   Window carries the 0.5 magnitude factor (0.25-0.25cos); Nyquist gets *2.
// blocks 17408..17535: D prep row n = blk-17408 (coalesced fp32 reads, LDS
//   permute k'=t*257+f <- f*17+t, bf16 pack, rowsum). LDS union with Z.
__global__ __launch_bounds__(256) void k_stft(const float* __restrict__ audio,
    const float* __restrict__ D, unsigned short* __restrict__ spec,
    float* __restrict__ psf, unsigned short* __restrict__ Dbf,
    float* __restrict__ rowsum){
  __shared__ __align__(16) char smraw[19712];   // max(4*616*8, 4369*4+256*4)
  const int tid = threadIdx.x;
  const int blk = blockIdx.x;
  if (blk >= 17408){
    // ---- D-prep branch ----
    float* row = (float*)smraw;                 // [4369]
    float* rs  = (float*)(smraw + 17476);       // [256]
    const int n = blk - 17408;
    float acc = 0.0f;
    for (int k = tid; k < 4369; k += 256){
      float v = D[(size_t)n*4369 + k];          // coalesced
      row[k] = v;
      acc += v;
    }
    rs[tid] = acc;
    __syncthreads();
    #pragma unroll
    for (int s = 128; s > 0; s >>= 1){
      if (tid < s) rs[tid] += rs[tid + s];
      __syncthreads();
    }
    if (tid == 0) rowsum[n] = rs[0];
    for (int i = tid; i < 1096; i += 256){
      int k0 = i*4;
      ushort4 pk;
      unsigned short v[4];
      #pragma unroll
      for (int u = 0; u < 4; u++){
        int kp = k0 + u;
        unsigned short r = 0;
        if (kp < 4369){
          int t = kp / 257, f = kp - t*257;
          r = f2bf(row[f*17 + t]);
        }
        v[u] = r;
      }
      pk.x = v[0]; pk.y = v[1]; pk.z = v[2]; pk.w = v[3];
      *(ushort4*)(Dbf + (size_t)n*4384 + k0) = pk;
    }
    return;
  }
  // ---- STFT branch ----
  f32x2 (*zb)[616] = (f32x2(*)[616])smraw;
  const int wid = tid >> 6;
  const int L = tid & 63;
  f32x2* Z = zb[wid];
  const int pair = blk*4 + wid;               // 0..69631
  const int fr0 = pair*2;
  const int b0 = fr0/17, t0 = fr0 - b0*17;
  const int fr1 = fr0 + 1;
  const int b1 = fr1/17, t1 = fr1 - b1*17;
  const float* sA = audio + (size_t)b0*3200 + t0*160;
  const float* sB = audio + (size_t)b1*3200 + t1*160;
  f32x2 z[8];
  // fused digit-reversed load + window; idx=8L+e -> r9 = baseRev+64e.
  // wind_e = 0.25 - 0.25 cos(th0 + e*pi/4); r^2 = i identities:
  // wind = {.25-.25c0, .25-.25c1, .25+.25s0, .25+.25s1,
  //         .25+.25c0, .25+.25c1, .25-.25s0, .25-.25s1}  (depth 2)
  {
    const int baseRev = ((L & 7) << 3) | (L >> 3);
    float th0 = (float)baseRev * TWO_PI_OVER_512;
    float c0 = __cosf(th0), s0 = __sinf(th0);
    float c1 = C8*(c0 - s0), s1 = C8*(s0 + c0);
    float wind[8] = {0.25f - 0.25f*c0, 0.25f - 0.25f*c1,
                     0.25f + 0.25f*s0, 0.25f + 0.25f*s1,
                     0.25f + 0.25f*c0, 0.25f + 0.25f*c1,
                     0.25f - 0.25f*s0, 0.25f - 0.25f*s1};
    #pragma unroll
    for (int e = 0; e < 8; e++){
      int r9 = baseRev + (e << 6);
      z[e] = (f32x2){sA[r9]*wind[e], sB[r9]*wind[e]};
    }
  }
  dft8p(z);
  {
    int s0i = 9*L + 5*(L >> 3);               // slot(8L), e contiguous
    #pragma unroll
    for (int e = 0; e < 8; e++) Z[s0i + e] = z[e];
  }
  // stage 1: i = g*64 + j + 8e -> slot = 77g + j + 9e ; W_64^{je} tree
  {
    int j = L & 7, g = L >> 3;
    int sb = 77*g + j;
    #pragma unroll
    for (int e = 0; e < 8; e++) z[e] = Z[sb + 9*e];
    float ang = (float)j * TWO_PI_OVER_64;
    twiddle_apply(z, (f32x2){__cosf(ang), __sinf(ang)});
    dft8p(z);
    #pragma unroll
    for (int e = 0; e < 8; e++) Z[sb + 9*e] = z[e];
  }
  // stage 2: i = L + 64e -> slot = L + (L>>3) + 77e ; lane L ends with Z[k=L+64f]
  {
    int sb = L + (L >> 3);
    #pragma unroll
    for (int e = 0; e < 8; e++) z[e] = Z[sb + 77*e];
    float ang = (float)L * TWO_PI_OVER_512;
    twiddle_apply(z, (f32x2){__cosf(ang), __sinf(ang)});
    dft8p(z);
  }
  // conj-partner exchange: partner of k=L+64f is lane (64-L)&63, reg 7-f (L>=1)
  f32x2 p[4];
  {
    const int partner = (64 - L) & 63;
    #pragma unroll
    for (int f = 0; f < 4; f++){
      p[f].x = __shfl(z[7-f].x, partner);
      p[f].y = __shfl(z[7-f].y, partner);
    }
    if (L == 0){                              // lane 0: partner regs are own (8-f)&7
      p[0] = z[0]; p[1] = z[7]; p[2] = z[6]; p[3] = z[5];
    }
  }
  unsigned short* dA = spec + (size_t)b0*4384 + t0*257;
  unsigned short* dB = spec + (size_t)b1*4384 + t1*257;
  f32x2 s1v = (f32x2){0.f, 0.f}, s2v = (f32x2){0.f, 0.f};
  #pragma unroll
  for (int f = 0; f < 4; f++){
    int k = L + 64*f;
    f32x2 A  = z[f] + (f32x2){p[f].x, -p[f].y};          // {zr+pr, zi-pi}
    f32x2 Bv = (f32x2){z[f].y, -z[f].x} + (f32x2){p[f].y, p[f].x}; // {zi+pi, pr-zr}
    float mA = sqrtf(A.x*A.x + A.y*A.y);      // 0.5 folded into window
    float mB = sqrtf(Bv.x*Bv.x + Bv.y*Bv.y);
    dA[k] = f2bf(mA);
    dB[k] = f2bf(mB);
    f32x2 m = (f32x2){mA, mB};
    s1v += m;
    s2v += m*m;
  }
  if (L == 0){                                // k=256: Z pre-halved -> *2 (no
    float mA = 2.0f*fabsf(z[4].x);            // conj-combine 0.5 at Nyquist)
    float mB = 2.0f*fabsf(z[4].y);
    dA[256] = f2bf(mA);
    dB[256] = f2bf(mB);
    s1v += (f32x2){mA, mB};
    s2v += (f32x2){mA*mA, mB*mB};
  }
  float s1A = s1v.x, s2A = s2v.x, s1B = s1v.y, s2B = s2v.y;
  #pragma unroll
  for (int off = 32; off > 0; off >>= 1){
    s1A += __shfl_xor(s1A, off);
    s2A += __shfl_xor(s2A, off);
    s1B += __shfl_xor(s1B, off);
    s2B += __shfl_xor(s2B, off);
  }
  if (L == 0)
    *(float4*)(psf + (size_t)fr0*2) = make_float4(s1A, s2A, s1B, s2B);
  if (t0 == 0 && L < 15) spec[(size_t)b0*4384 + 4369 + L] = 0;
  if (t1 == 0 && L < 15) spec[(size_t)b1*4384 + 4369 + L] = 0;
}

// ---------------- K4: partial GEMM spec·Dᵀ ‖ gram partials (fused) -----------
// grid (128, 9), 128 thr (2 waves).
// y<8: GEMM k-slice, wave = rows [mbase, mbase+32): 16 MFMA : 10 loads / step.
// y==8, x<64: gram partial strip x>>3, ks x&7 (17 iters - matched length, no
//   serial tail). Wave w computes nt w*4..w*4+3. Same pgram layout + ascending
//   k-order as the old k_gram_mm -> gram_fin result bit-identical.
__global__ __launch_bounds__(128) void k_gemm(const unsigned short* __restrict__ spec,
    const unsigned short* __restrict__ Dbf, float* __restrict__ part,
    float* __restrict__ pgram){
  const int lane = threadIdx.x & 63;
  const int c = lane & 15, q = lane >> 4;
  const int wv = threadIdx.x >> 6;
  if (blockIdx.y == 8){
    if (blockIdx.x >= 64) return;
    const int x = blockIdx.x >> 3;            // strip 0..7
    const int ks = blockIdx.x & 7;            // 0..7
    const unsigned short* ap = Dbf + (size_t)(x*16 + c)*4384 + q*8;
    const unsigned short* bp = Dbf + (size_t)c*4384 + q*8;
    const int t0 = ks*17, t1 = (ks == 7) ? 137 : t0 + 17;
    f32x4 acc[4];
    #pragma unroll
    for (int i = 0; i < 4; i++) acc[i] = (f32x4){0.f,0.f,0.f,0.f};
    for (int tt = t0; tt < t1; tt++){
      const int k0 = tt*32;
      bf16x8 af = *(const bf16x8*)(ap + k0);
      #pragma unroll
      for (int i = 0; i < 4; i++){
        const int nt = wv*4 + i;
        bf16x8 bfr = *(const bf16x8*)(bp + (size_t)nt*16*4384 + k0);
        acc[i] = __builtin_amdgcn_mfma_f32_16x16x32_bf16(af, bfr, acc[i], 0, 0, 0);
      }
    }
    #pragma unroll
    for (int i = 0; i < 4; i++){
      const int nt = wv*4 + i;
      #pragma unroll
      for (int r = 0; r < 4; r++)
        pgram[(size_t)(ks*128 + x*16 + q*4 + r)*128 + nt*16 + c] = acc[i][r];
    }
    return;
  }
  const int mtile = blockIdx.x;               // 0..127 (64 rows per WG)
  const int ks = blockIdx.y;                  // 0..7
  const int mbase = mtile*64 + wv*32;
  const unsigned short* ap0 = spec + (size_t)(mbase + c)*4384 + q*8;
  const unsigned short* ap1 = ap0 + (size_t)16*4384;
  const unsigned short* bp  = Dbf + (size_t)c*4384 + q*8;
  const int t0 = ks*17, t1 = (ks == 7) ? 137 : t0 + 17;
  f32x4 acc[2][8];
  #pragma unroll
  for (int ar = 0; ar < 2; ar++)
    #pragma unroll
    for (int nt = 0; nt < 8; nt++) acc[ar][nt] = (f32x4){0.f,0.f,0.f,0.f};
  int k0 = t0*32;
  bf16x8 aC0 = *(const bf16x8*)(ap0 + k0);
  bf16x8 aC1 = *(const bf16x8*)(ap1 + k0);
  bf16x8 bC[8];
  #pragma unroll
  for (int nt = 0; nt < 8; nt++)
    bC[nt] = *(const bf16x8*)(bp + (size_t)nt*16*4384 + k0);
  for (int tt = t0; tt < t1; tt++){
    const int tn = (tt + 1 < t1) ? tt + 1 : tt;
    const int kn = tn*32;
    bf16x8 aN0 = *(const bf16x8*)(ap0 + kn);
    bf16x8 aN1 = *(const bf16x8*)(ap1 + kn);
    bf16x8 bN[8];
    #pragma unroll
    for (int nt = 0; nt < 8; nt++)
      bN[nt] = *(const bf16x8*)(bp + (size_t)nt*16*4384 + kn);
    #pragma unroll
    for (int nt = 0; nt < 8; nt++){
      acc[0][nt] = __builtin_amdgcn_mfma_f32_16x16x32_bf16(aC0, bC[nt], acc[0][nt], 0, 0, 0);
      acc[1][nt] = __builtin_amdgcn_mfma_f32_16x16x32_bf16(aC1, bC[nt], acc[1][nt], 0, 0, 0);
    }
    aC0 = aN0; aC1 = aN1;
    #pragma unroll
    for (int nt = 0; nt < 8; nt++) bC[nt] = bN[nt];
  }
  // part[ks][n][m]: n = nt*16+c, m = mbase + ar*16 + q*4 + r
  #pragma unroll
  for (int nt = 0; nt < 8; nt++){
    float* b0 = part + ((size_t)(ks*128 + nt*16 + c))*8192 + mbase + q*4;
    *(f32x4*)(b0)      = acc[0][nt];
    *(f32x4*)(b0 + 16) = acc[1][nt];
  }
}

// deterministic fixed-order sum -> exactly symmetric (MFMA k-order identical for (x,y)/(y,x))
__global__ __launch_bounds__(128) void k_gram_fin(const float* __restrict__ pgram,
    unsigned short* __restrict__ gram_bf){
  const int x = blockIdx.x, y = threadIdx.x;
  float g = ((pgram[(size_t)x*128+y]        + pgram[(size_t)(128+x)*128+y])
          +  (pgram[(size_t)(256+x)*128+y]  + pgram[(size_t)(384+x)*128+y]))
          + ((pgram[(size_t)(512+x)*128+y]  + pgram[(size_t)(640+x)*128+y])
          +  (pgram[(size_t)(768+x)*128+y]  + pgram[(size_t)(896+x)*128+y]));
  if (x == y) g -= 1.0f;
  gram_bf[x*136 + y] = f2bf(g);
}

// ---------------- K5: LCA, 50 iters. rᵀ = G·aᵀ; 4 waves x 32 gram rows ------
// 512 blocks x 256 thr: block = 16 samples; wave wv owns rows [wv*32, wv*32+32).
// a exchanged via double-buffered LDS, ONE barrier per iter.
__global__ __launch_bounds__(256) void k_lca(const float* __restrict__ part,
    const unsigned short* __restrict__ gram_bf, const float* __restrict__ rowsum,
    const float* __restrict__ psf, float* __restrict__ out){
  __shared__ unsigned short A[2][16*136];
  const int tid = threadIdx.x, wv = tid >> 6, lane = tid & 63;
  const int c = lane & 15, q = lane >> 4;
  const int sg = blockIdx.x*16 + c;
  // moments: sum 17 per-frame (s1,s2) pairs (fp32, fixed order)
  const float* pf = psf + (size_t)sg*34;
  float S1 = 0.f, S2 = 0.f;
  #pragma unroll
  for (int t = 0; t < 17; t++){
    S1 += pf[2*t];
    S2 += pf[2*t + 1];
  }
  const float mus = S1 / 4369.0f;
  float var = (S2 - S1*S1/4369.0f) / 4368.0f;
  var = fmaxf(var, 0.0f);
  const float invs = 1.0f / (sqrtf(var) + 1e-8f);
  const int nb = wv*32;
  bf16x8 Gf[2][4];                            // A-frags of G rows [nb, nb+32)
  #pragma unroll
  for (int rt = 0; rt < 2; rt++)
    #pragma unroll
    for (int kt = 0; kt < 4; kt++)
      Gf[rt][kt] = *(const bf16x8*)(gram_bf + (size_t)(nb + rt*16 + c)*136 + kt*32 + q*8);
  f32x4 U[2], Bb[2];
  #pragma unroll
  for (int rt = 0; rt < 2; rt++){
    #pragma unroll
    for (int r = 0; r < 4; r++){
      int n = nb + rt*16 + q*4 + r;
      float S = 0.f;
      #pragma unroll
      for (int s = 0; s < 8; s++)
        S += part[((size_t)(s*128 + n))*8192 + sg];
      Bb[rt][r] = invs * (S - mus * rowsum[n]);
      U[rt][r] = 0.0f;
    }
  }
  for (int it = 0; it < 50; it++){
    unsigned short* Ab = A[it & 1];
    #pragma unroll
    for (int rt = 0; rt < 2; rt++){
      ushort4 pk;
      pk.x = f2bf(sshrink(U[rt][0]));
      pk.y = f2bf(sshrink(U[rt][1]));
      pk.z = f2bf(sshrink(U[rt][2]));
      pk.w = f2bf(sshrink(U[rt][3]));
      *(ushort4*)(Ab + c*136 + nb + rt*16 + q*4) = pk;
    }
    __syncthreads();
    bf16x8 af[4];
    #pragma unroll
    for (int kt = 0; kt < 4; kt++)            // B-frag: aᵀ[k][sample=c]
      af[kt] = *(const bf16x8*)(Ab + c*136 + kt*32 + q*8);
    f32x4 R[2];
    R[0] = (f32x4){0.f,0.f,0.f,0.f};
    R[1] = (f32x4){0.f,0.f,0.f,0.f};
    #pragma unroll
    for (int kt = 0; kt < 4; kt++)            // kt outer: R[0],R[1] chains interleave
      #pragma unroll
      for (int rt = 0; rt < 2; rt++)
        R[rt] = __builtin_amdgcn_mfma_f32_16x16x32_bf16(Gf[rt][kt], af[kt], R[rt], 0, 0, 0);
    #pragma unroll
    for (int rt = 0; rt < 2; rt++){
      #pragma unroll
      for (int r = 0; r < 4; r++){
        float u = U[rt][r];
        U[rt][r] = u + (Bb[rt][r] - u - R[rt][r]) * 0.1f;
      }
    }
  }
  #pragma unroll
  for (int rt = 0; rt < 2; rt++){
    float4 o;
    o.x = sshrink(U[rt][0]);
    o.y = sshrink(U[rt][1]);
    o.z = sshrink(U[rt][2]);
    o.w = sshrink(U[rt][3]);
    *(float4*)(out + (size_t)sg*128 + nb + rt*16 + q*4) = o;
  }
}

// ---------------- launch ----------------
extern "C" void kernel_launch(void* const* d_in, const int* in_sizes, int n_in,
                              void* d_out, int out_size, void* d_ws, size_t ws_size,
                              hipStream_t stream){
  const float* audio = (const float*)d_in[0];   // 8192*3200
  const float* D     = (const float*)d_in[1];   // 128*4369
  float* out = (float*)d_out;                   // 8192*128 f32
  char* ws = (char*)d_ws;
  // workspace layout, total ~108.2 MB
  unsigned short* spec   = (unsigned short*)(ws);               // 71,827,456
  float*          part   = (float*)(ws + 71827456);             // 33,554,432 (8 slices)
  unsigned short* Dbf    = (unsigned short*)(ws + 105381888);   // 1,122,304
  unsigned short* gram   = (unsigned short*)(ws + 106504192);   // 34,816
  float*          pgram  = (float*)(ws + 106539008);            // 524,288
  float*          rowsum = (float*)(ws + 107063296);            // 512
  float*          psf    = (float*)(ws + 107063808);            // 1,114,112 (8192*17*2)

  k_stft    <<<17536, 256, 0, stream>>>(audio, D, spec, psf, Dbf, rowsum);
  k_gemm    <<<dim3(128, 9, 1), 128, 0, stream>>>(spec, Dbf, part, pgram);
  k_gram_fin<<<128, 128, 0, stream>>>(pgram, gram);
  k_lca     <<<512, 256, 0, stream>>>(part, gram, rowsum, psf, out);
}